// Round 1
// baseline (3531.639 us; speedup 1.0000x reference)
//
#include <hip/hip_runtime.h>
#include <math.h>

#define BB 4
#define CC 128
#define CRR 32
#define DD 24
#define HH 96
#define WW 320
#define HWW (HH*WW)   // 30720

// ---------------------------------------------------------------------------
// Kernel 1: q/k 1x1 conv + l2norm.  One thread per pixel.
// Weights fetched with uniform indices -> scalar (SMEM) loads.
// ---------------------------------------------------------------------------
__global__ __launch_bounds__(256) void qk_kernel(
    const float* __restrict__ t_feat, const float* __restrict__ s_feat,
    const float* __restrict__ q_w, const float* __restrict__ q_b,
    const float* __restrict__ k_w, const float* __restrict__ k_b,
    float* __restrict__ ws_q, float* __restrict__ ws_k)
{
    int p = blockIdx.x * 256 + threadIdx.x;        // 0..122879
    int b = p / HWW, rem = p % HWW;

    float accq[CRR], acck[CRR];
    #pragma unroll
    for (int o = 0; o < CRR; ++o) { accq[o] = q_b[o]; acck[o] = k_b[o]; }

    const float* tp = t_feat + (size_t)b * CC * HWW + rem;
    const float* sp = s_feat + (size_t)b * CC * HWW + rem;

    #pragma unroll 4
    for (int c = 0; c < CC; ++c) {
        float tv = tp[(size_t)c * HWW];
        float sv = sp[(size_t)c * HWW];
        #pragma unroll
        for (int o = 0; o < CRR; ++o) {
            accq[o] = fmaf(tv, q_w[o * CC + c], accq[o]);
            acck[o] = fmaf(sv, k_w[o * CC + c], acck[o]);
        }
    }
    float nq = 0.f, nk = 0.f;
    #pragma unroll
    for (int o = 0; o < CRR; ++o) { nq = fmaf(accq[o], accq[o], nq); nk = fmaf(acck[o], acck[o], nk); }
    float invq = 1.f / fmaxf(sqrtf(nq), 1e-12f);
    float invk = 1.f / fmaxf(sqrtf(nk), 1e-12f);
    #pragma unroll
    for (int o = 0; o < CRR; ++o) {
        ws_q[((size_t)b * CRR + o) * HWW + rem] = accq[o] * invq;
        ws_k[((size_t)b * CRR + o) * HWW + rem] = acck[o] * invk;
    }
}

// ---------------------------------------------------------------------------
// Kernel 2: plane-sweep warp + sim + softmax (-> prob out) + cost +
//           cost-expand (1x1) + alpha fuse -> fused (ws).
// One thread per pixel.  All per-d arrays fully unrolled (register-resident).
// ---------------------------------------------------------------------------
__global__ __launch_bounds__(256) void wsc_kernel(
    const float* __restrict__ t_feat,
    const float* __restrict__ directs, const int* __restrict__ image_shape,
    const float* __restrict__ ce_w, const float* __restrict__ ce_b,
    const float* __restrict__ fa_w, const float* __restrict__ fa_b,
    const float* __restrict__ ws_q, const float* __restrict__ ws_k,
    float* __restrict__ prob_out, float* __restrict__ ws_fused)
{
    int p = blockIdx.x * 256 + threadIdx.x;
    int b = p / HWW, rem = p % HWW;
    int h = rem / WW, w = rem % WW;

    float rel = 640.0f / (float)image_shape[3];
    float fscale = rel * directs[b] * (float)(WW - 1);   // shift(d) = disp_d * fscale

    float q[CRR];
    #pragma unroll
    for (int c = 0; c < CRR; ++c) q[c] = ws_q[((size_t)b * CRR + c) * HWW + rem];

    const float* kbase = ws_k + (size_t)b * CRR * HWW + h * WW;

    float sim[DD];
    #pragma unroll
    for (int d = 0; d < DD; ++d) {
        float disp = 0.3f * (float)d / 23.0f;
        float fx = fminf(fmaxf((float)w + disp * fscale, 0.f), (float)(WW - 1));
        int ix0 = (int)floorf(fx);
        int ix1 = min(ix0 + 1, WW - 1);
        float w1 = fx - (float)ix0;
        float s = 0.f;
        #pragma unroll
        for (int c = 0; c < CRR; ++c) {
            float k0 = kbase[c * HWW + ix0];
            float k1 = kbase[c * HWW + ix1];
            s = fmaf(q[c], fmaf(w1, k1 - k0, k0), s);
        }
        sim[d] = s;
    }
    // softmax over d
    float m = sim[0];
    #pragma unroll
    for (int d = 1; d < DD; ++d) m = fmaxf(m, sim[d]);
    float sum = 0.f;
    #pragma unroll
    for (int d = 0; d < DD; ++d) { sim[d] = expf(sim[d] - m); sum += sim[d]; }
    float inv = 1.f / sum;
    #pragma unroll
    for (int d = 0; d < DD; ++d) {
        sim[d] *= inv;                                    // sim now holds prob
        prob_out[((size_t)b * DD + d) * HWW + rem] = sim[d];
    }
    // cost = sum_d prob_d * warped
    float cost[CRR];
    #pragma unroll
    for (int c = 0; c < CRR; ++c) cost[c] = 0.f;
    #pragma unroll
    for (int d = 0; d < DD; ++d) {
        float disp = 0.3f * (float)d / 23.0f;
        float fx = fminf(fmaxf((float)w + disp * fscale, 0.f), (float)(WW - 1));
        int ix0 = (int)floorf(fx);
        int ix1 = min(ix0 + 1, WW - 1);
        float w1 = fx - (float)ix0;
        float pr = sim[d];
        #pragma unroll
        for (int c = 0; c < CRR; ++c) {
            float k0 = kbase[c * HWW + ix0];
            float k1 = kbase[c * HWW + ix1];
            cost[c] = fmaf(pr, fmaf(w1, k1 - k0, k0), cost[c]);
        }
    }
    // cost-expand + alpha accumulation
    const float* tp = t_feat + (size_t)b * CC * HWW + rem;
    float at = 0.f, ac = 0.f;
    #pragma unroll 1
    for (int oc = 0; oc < CC; ++oc) {
        float ce = ce_b[oc];
        #pragma unroll
        for (int c = 0; c < CRR; ++c) ce = fmaf(cost[c], ce_w[oc * CRR + c], ce);
        at = fmaf(fa_w[oc], tp[(size_t)oc * HWW], at);
        ac = fmaf(fa_w[CC + oc], ce, ac);
    }
    float alpha = 1.f / (1.f + expf(-(at + ac + fa_b[0])));
    // fused = alpha*t + (1-alpha)*cost_exp  (recompute ce, cheap)
    #pragma unroll 1
    for (int oc = 0; oc < CC; ++oc) {
        float ce = ce_b[oc];
        #pragma unroll
        for (int c = 0; c < CRR; ++c) ce = fmaf(cost[c], ce_w[oc * CRR + c], ce);
        float tv = tp[(size_t)oc * HWW];
        ws_fused[((size_t)b * CC + oc) * HWW + rem] = alpha * tv + (1.f - alpha) * ce;
    }
}

// ---------------------------------------------------------------------------
// Kernel 3: 3x3 reflect-pad conv (128->128), fp32.
// Block = (b, h, 64-px w-tile); 256 thr = 64 px x 4 oc-groups (32 oc each).
// Input slab (32 ic x 3 rows x 66 cols) staged in LDS; weights via
// wave-uniform scalar loads (readfirstlane-forced uniform base).
// ---------------------------------------------------------------------------
#define ICCHUNK 32
__global__ __launch_bounds__(256) void conv_kernel(
    const float* __restrict__ ws_fused, const float* __restrict__ redu_w,
    float* __restrict__ out_conv)
{
    __shared__ float tile[ICCHUNK][3][66];
    int px = threadIdx.x & 63;
    int g  = __builtin_amdgcn_readfirstlane((int)(threadIdx.x >> 6));  // 0..3, wave-uniform
    int w0 = blockIdx.x * 64;
    int h  = blockIdx.y;
    int b  = blockIdx.z;

    float acc[32];
    #pragma unroll
    for (int o = 0; o < 32; ++o) acc[o] = 0.f;

    const float* wg = redu_w + (size_t)(g * 32) * CC * 9;
    const float* fb = ws_fused + (size_t)b * CC * HWW;

    for (int ic0 = 0; ic0 < CC; ic0 += ICCHUNK) {
        // stage input slab with reflect padding
        for (int idx = threadIdx.x; idx < ICCHUNK * 3 * 66; idx += 256) {
            int icl = idx / (3 * 66);
            int rr  = (idx / 66) % 3;
            int cc  = idx % 66;
            int row = h - 1 + rr;
            row = row < 0 ? 1 : (row > HH - 1 ? HH - 2 : row);
            int col = w0 - 1 + cc;
            col = col < 0 ? -col : (col > WW - 1 ? 2 * (WW - 1) - col : col);
            tile[icl][rr][cc] = fb[(size_t)(ic0 + icl) * HWW + row * WW + col];
        }
        __syncthreads();
        #pragma unroll 2
        for (int icl = 0; icl < ICCHUNK; ++icl) {
            float x[9];
            #pragma unroll
            for (int rr = 0; rr < 3; ++rr)
                #pragma unroll
                for (int j = 0; j < 3; ++j)
                    x[rr * 3 + j] = tile[icl][rr][px + j];
            int ic = ic0 + icl;
            #pragma unroll
            for (int oc = 0; oc < 32; ++oc) {
                const float* wv = wg + (size_t)(oc * CC + ic) * 9;
                float a = acc[oc];
                #pragma unroll
                for (int j = 0; j < 9; ++j) a = fmaf(x[j], wv[j], a);
                acc[oc] = a;
            }
        }
        __syncthreads();
    }
    #pragma unroll
    for (int oc = 0; oc < 32; ++oc)
        out_conv[((size_t)b * CC + g * 32 + oc) * HWW + h * WW + w0 + px] = acc[oc];
}

// ---------------------------------------------------------------------------
// Kernel 4: per-(b,c) plane mean
// ---------------------------------------------------------------------------
__global__ __launch_bounds__(256) void pool_kernel(
    const float* __restrict__ conv, float* __restrict__ pool)
{
    int plane = blockIdx.x;                // 0..511
    const float* p = conv + (size_t)plane * HWW;
    float s = 0.f;
    for (int i = threadIdx.x; i < HWW; i += 256) s += p[i];
    #pragma unroll
    for (int off = 32; off; off >>= 1) s += __shfl_down(s, off);
    __shared__ float wsum[4];
    if ((threadIdx.x & 63) == 0) wsum[threadIdx.x >> 6] = s;
    __syncthreads();
    if (threadIdx.x == 0)
        pool[plane] = (wsum[0] + wsum[1] + wsum[2] + wsum[3]) / (float)HWW;
}

// ---------------------------------------------------------------------------
// Kernel 5: SE MLP -> gate
// ---------------------------------------------------------------------------
__global__ __launch_bounds__(256) void segate_kernel(
    const float* __restrict__ pool, const float* __restrict__ w1,
    const float* __restrict__ w2, float* __restrict__ gate)
{
    __shared__ float hidden[BB * 8];
    int t = threadIdx.x;
    if (t < BB * 8) {
        int b = t / 8, r = t % 8;
        float s = 0.f;
        for (int c = 0; c < CC; ++c) s = fmaf(pool[b * CC + c], w1[r * CC + c], s);
        hidden[t] = fmaxf(s, 0.f);
    }
    __syncthreads();
    for (int idx = t; idx < BB * CC; idx += 256) {
        int b = idx / CC, c = idx % CC;
        float s = 0.f;
        #pragma unroll
        for (int r = 0; r < 8; ++r) s = fmaf(hidden[b * 8 + r], w2[c * 8 + r], s);
        gate[idx] = 1.f / (1.f + expf(-s));
    }
}

// ---------------------------------------------------------------------------
// Kernel 6: out = elu(conv * gate)  (in place on d_out)
// ---------------------------------------------------------------------------
__global__ __launch_bounds__(256) void elu_kernel(
    float* __restrict__ out, const float* __restrict__ gate)
{
    size_t i = (size_t)blockIdx.x * 256 + threadIdx.x;
    int plane = (int)(i / HWW);            // b*128+c
    float x = out[i] * gate[plane];
    out[i] = x > 0.f ? x : expm1f(x);
}

// ---------------------------------------------------------------------------
extern "C" void kernel_launch(void* const* d_in, const int* in_sizes, int n_in,
                              void* d_out, int out_size, void* d_ws, size_t ws_size,
                              hipStream_t stream)
{
    (void)in_sizes; (void)n_in; (void)out_size; (void)ws_size;
    const float* t_feat      = (const float*)d_in[0];
    const float* s_feat      = (const float*)d_in[1];
    const float* directs     = (const float*)d_in[2];
    const int*   image_shape = (const int*)d_in[3];
    const float* q_w  = (const float*)d_in[4];
    const float* q_b  = (const float*)d_in[5];
    const float* k_w  = (const float*)d_in[6];
    const float* k_b  = (const float*)d_in[7];
    const float* ce_w = (const float*)d_in[8];
    const float* ce_b = (const float*)d_in[9];
    const float* fa_w = (const float*)d_in[10];
    const float* fa_b = (const float*)d_in[11];
    const float* redu_w = (const float*)d_in[12];
    const float* se_w1  = (const float*)d_in[13];
    const float* se_w2  = (const float*)d_in[14];

    float* out      = (float*)d_out;
    float* prob_out = out + (size_t)BB * CC * HWW;   // second output region

    float* ws       = (float*)d_ws;
    float* ws_q     = ws;
    float* ws_k     = ws + (size_t)BB * CRR * HWW;
    float* ws_fused = ws + 2ull * BB * CRR * HWW;
    float* ws_pool  = ws_fused + (size_t)BB * CC * HWW;
    float* ws_gate  = ws_pool + BB * CC;

    qk_kernel<<<480, 256, 0, stream>>>(t_feat, s_feat, q_w, q_b, k_w, k_b, ws_q, ws_k);
    wsc_kernel<<<480, 256, 0, stream>>>(t_feat, directs, image_shape,
                                        ce_w, ce_b, fa_w, fa_b,
                                        ws_q, ws_k, prob_out, ws_fused);
    conv_kernel<<<dim3(WW / 64, HH, BB), 256, 0, stream>>>(ws_fused, redu_w, out);
    pool_kernel<<<BB * CC, 256, 0, stream>>>(out, ws_pool);
    segate_kernel<<<1, 256, 0, stream>>>(ws_pool, se_w1, se_w2, ws_gate);
    elu_kernel<<<(BB * CC * HWW) / 256, 256, 0, stream>>>(out, ws_gate);
}

// Round 2
// 1840.053 us; speedup vs baseline: 1.9193x; 1.9193x over previous
//
#include <hip/hip_runtime.h>
#include <math.h>

#define BB 4
#define CC 128
#define CRR 32
#define DD 24
#define HH 96
#define WW 320
#define HWW (HH*WW)   // 30720

// ---------------------------------------------------------------------------
// Kernel 1: q/k 1x1 conv + l2norm.  One thread per pixel.
// ---------------------------------------------------------------------------
__global__ __launch_bounds__(256) void qk_kernel(
    const float* __restrict__ t_feat, const float* __restrict__ s_feat,
    const float* __restrict__ q_w, const float* __restrict__ q_b,
    const float* __restrict__ k_w, const float* __restrict__ k_b,
    float* __restrict__ ws_q, float* __restrict__ ws_k)
{
    int p = blockIdx.x * 256 + threadIdx.x;        // 0..122879
    int b = p / HWW, rem = p % HWW;

    float accq[CRR], acck[CRR];
    #pragma unroll
    for (int o = 0; o < CRR; ++o) { accq[o] = q_b[o]; acck[o] = k_b[o]; }

    const float* tp = t_feat + (size_t)b * CC * HWW + rem;
    const float* sp = s_feat + (size_t)b * CC * HWW + rem;

    #pragma unroll 4
    for (int c = 0; c < CC; ++c) {
        float tv = tp[(size_t)c * HWW];
        float sv = sp[(size_t)c * HWW];
        #pragma unroll
        for (int o = 0; o < CRR; ++o) {
            accq[o] = fmaf(tv, q_w[o * CC + c], accq[o]);
            acck[o] = fmaf(sv, k_w[o * CC + c], acck[o]);
        }
    }
    float nq = 0.f, nk = 0.f;
    #pragma unroll
    for (int o = 0; o < CRR; ++o) { nq = fmaf(accq[o], accq[o], nq); nk = fmaf(acck[o], acck[o], nk); }
    float invq = 1.f / fmaxf(sqrtf(nq), 1e-12f);
    float invk = 1.f / fmaxf(sqrtf(nk), 1e-12f);
    #pragma unroll
    for (int o = 0; o < CRR; ++o) {
        ws_q[((size_t)b * CRR + o) * HWW + rem] = accq[o] * invq;
        ws_k[((size_t)b * CRR + o) * HWW + rem] = acck[o] * invk;
    }
}

// ---------------------------------------------------------------------------
// Kernel 2a: sim = q . warp(k)  -> softmax over d -> prob (to d_out)
// One thread per pixel.  Registers: q[32] + sim[24] ~ 80 VGPR.
// ---------------------------------------------------------------------------
__global__ __launch_bounds__(256) void sim_kernel(
    const float* __restrict__ directs, const int* __restrict__ image_shape,
    const float* __restrict__ ws_q, const float* __restrict__ ws_k,
    float* __restrict__ prob_out)
{
    int p = blockIdx.x * 256 + threadIdx.x;
    int b = p / HWW, rem = p % HWW;
    int h = rem / WW, w = rem % WW;

    float rel = 640.0f / (float)image_shape[3];
    float fscale = rel * directs[b] * (float)(WW - 1);

    float q[CRR];
    #pragma unroll
    for (int c = 0; c < CRR; ++c) q[c] = ws_q[((size_t)b * CRR + c) * HWW + rem];

    const float* kbase = ws_k + (size_t)b * CRR * HWW + h * WW;

    float sim[DD];
    #pragma unroll 2
    for (int d = 0; d < DD; ++d) {
        float disp = 0.3f * (float)d / 23.0f;
        float fx = fminf(fmaxf((float)w + disp * fscale, 0.f), (float)(WW - 1));
        int ix0 = (int)floorf(fx);
        int ix1 = min(ix0 + 1, WW - 1);
        float w1 = fx - (float)ix0;
        float s = 0.f;
        #pragma unroll
        for (int c = 0; c < CRR; ++c) {
            float k0 = kbase[c * HWW + ix0];
            float k1 = kbase[c * HWW + ix1];
            s = fmaf(q[c], fmaf(w1, k1 - k0, k0), s);
        }
        sim[d] = s;
    }
    float m = sim[0];
    #pragma unroll
    for (int d = 1; d < DD; ++d) m = fmaxf(m, sim[d]);
    float sum = 0.f;
    #pragma unroll
    for (int d = 0; d < DD; ++d) { sim[d] = expf(sim[d] - m); sum += sim[d]; }
    float inv = 1.f / sum;
    #pragma unroll
    for (int d = 0; d < DD; ++d)
        prob_out[((size_t)b * DD + d) * HWW + rem] = sim[d] * inv;
}

// ---------------------------------------------------------------------------
// Kernel 2b: cost[c] = sum_d prob_d * warp(k)[c]  -> ws_cost planes
// One thread per pixel.  Registers: cost[32] + temps ~ 50 VGPR.
// ---------------------------------------------------------------------------
__global__ __launch_bounds__(256) void cost_kernel(
    const float* __restrict__ directs, const int* __restrict__ image_shape,
    const float* __restrict__ ws_k, const float* __restrict__ prob_out,
    float* __restrict__ ws_cost)
{
    int p = blockIdx.x * 256 + threadIdx.x;
    int b = p / HWW, rem = p % HWW;
    int h = rem / WW, w = rem % WW;

    float rel = 640.0f / (float)image_shape[3];
    float fscale = rel * directs[b] * (float)(WW - 1);

    const float* kbase = ws_k + (size_t)b * CRR * HWW + h * WW;

    float cost[CRR];
    #pragma unroll
    for (int c = 0; c < CRR; ++c) cost[c] = 0.f;

    #pragma unroll 2
    for (int d = 0; d < DD; ++d) {
        float pr = prob_out[((size_t)b * DD + d) * HWW + rem];
        float disp = 0.3f * (float)d / 23.0f;
        float fx = fminf(fmaxf((float)w + disp * fscale, 0.f), (float)(WW - 1));
        int ix0 = (int)floorf(fx);
        int ix1 = min(ix0 + 1, WW - 1);
        float w1 = fx - (float)ix0;
        #pragma unroll
        for (int c = 0; c < CRR; ++c) {
            float k0 = kbase[c * HWW + ix0];
            float k1 = kbase[c * HWW + ix1];
            cost[c] = fmaf(pr, fmaf(w1, k1 - k0, k0), cost[c]);
        }
    }
    #pragma unroll
    for (int c = 0; c < CRR; ++c)
        ws_cost[((size_t)b * CRR + c) * HWW + rem] = cost[c];
}

// ---------------------------------------------------------------------------
// Kernel 2c: cost-expand (1x1, 32->128) + alpha (sigmoid) + fuse -> ws_fused
// One thread per pixel.  ce recomputed in the 2nd oc pass (cheap, reg-light).
// ---------------------------------------------------------------------------
__global__ __launch_bounds__(256) void fuse_kernel(
    const float* __restrict__ t_feat,
    const float* __restrict__ ce_w, const float* __restrict__ ce_b,
    const float* __restrict__ fa_w, const float* __restrict__ fa_b,
    const float* __restrict__ ws_cost, float* __restrict__ ws_fused)
{
    int p = blockIdx.x * 256 + threadIdx.x;
    int b = p / HWW, rem = p % HWW;

    float cost[CRR];
    #pragma unroll
    for (int c = 0; c < CRR; ++c) cost[c] = ws_cost[((size_t)b * CRR + c) * HWW + rem];

    const float* tp = t_feat + (size_t)b * CC * HWW + rem;
    float at = 0.f, ac = 0.f;
    #pragma unroll 1
    for (int oc = 0; oc < CC; ++oc) {
        float ce = ce_b[oc];
        #pragma unroll
        for (int c = 0; c < CRR; ++c) ce = fmaf(cost[c], ce_w[oc * CRR + c], ce);
        at = fmaf(fa_w[oc], tp[(size_t)oc * HWW], at);
        ac = fmaf(fa_w[CC + oc], ce, ac);
    }
    float alpha = 1.f / (1.f + expf(-(at + ac + fa_b[0])));
    #pragma unroll 1
    for (int oc = 0; oc < CC; ++oc) {
        float ce = ce_b[oc];
        #pragma unroll
        for (int c = 0; c < CRR; ++c) ce = fmaf(cost[c], ce_w[oc * CRR + c], ce);
        float tv = tp[(size_t)oc * HWW];
        ws_fused[((size_t)b * CC + oc) * HWW + rem] = alpha * tv + (1.f - alpha) * ce;
    }
}

// ---------------------------------------------------------------------------
// Kernel 3: 3x3 reflect-pad conv (128->128), fp32.
// ---------------------------------------------------------------------------
#define ICCHUNK 32
__global__ __launch_bounds__(256) void conv_kernel(
    const float* __restrict__ ws_fused, const float* __restrict__ redu_w,
    float* __restrict__ out_conv)
{
    __shared__ float tile[ICCHUNK][3][66];
    int px = threadIdx.x & 63;
    int g  = __builtin_amdgcn_readfirstlane((int)(threadIdx.x >> 6));  // 0..3, wave-uniform
    int w0 = blockIdx.x * 64;
    int h  = blockIdx.y;
    int b  = blockIdx.z;

    float acc[32];
    #pragma unroll
    for (int o = 0; o < 32; ++o) acc[o] = 0.f;

    const float* wg = redu_w + (size_t)(g * 32) * CC * 9;
    const float* fb = ws_fused + (size_t)b * CC * HWW;

    for (int ic0 = 0; ic0 < CC; ic0 += ICCHUNK) {
        for (int idx = threadIdx.x; idx < ICCHUNK * 3 * 66; idx += 256) {
            int icl = idx / (3 * 66);
            int rr  = (idx / 66) % 3;
            int cc  = idx % 66;
            int row = h - 1 + rr;
            row = row < 0 ? 1 : (row > HH - 1 ? HH - 2 : row);
            int col = w0 - 1 + cc;
            col = col < 0 ? -col : (col > WW - 1 ? 2 * (WW - 1) - col : col);
            tile[icl][rr][cc] = fb[(size_t)(ic0 + icl) * HWW + row * WW + col];
        }
        __syncthreads();
        #pragma unroll 2
        for (int icl = 0; icl < ICCHUNK; ++icl) {
            float x[9];
            #pragma unroll
            for (int rr = 0; rr < 3; ++rr)
                #pragma unroll
                for (int j = 0; j < 3; ++j)
                    x[rr * 3 + j] = tile[icl][rr][px + j];
            int ic = ic0 + icl;
            #pragma unroll
            for (int oc = 0; oc < 32; ++oc) {
                const float* wv = wg + (size_t)(oc * CC + ic) * 9;
                float a = acc[oc];
                #pragma unroll
                for (int j = 0; j < 9; ++j) a = fmaf(x[j], wv[j], a);
                acc[oc] = a;
            }
        }
        __syncthreads();
    }
    #pragma unroll
    for (int oc = 0; oc < 32; ++oc)
        out_conv[((size_t)b * CC + g * 32 + oc) * HWW + h * WW + w0 + px] = acc[oc];
}

// ---------------------------------------------------------------------------
// Kernel 4: per-(b,c) plane mean
// ---------------------------------------------------------------------------
__global__ __launch_bounds__(256) void pool_kernel(
    const float* __restrict__ conv, float* __restrict__ pool)
{
    int plane = blockIdx.x;                // 0..511
    const float* p = conv + (size_t)plane * HWW;
    float s = 0.f;
    for (int i = threadIdx.x; i < HWW; i += 256) s += p[i];
    #pragma unroll
    for (int off = 32; off; off >>= 1) s += __shfl_down(s, off);
    __shared__ float wsum[4];
    if ((threadIdx.x & 63) == 0) wsum[threadIdx.x >> 6] = s;
    __syncthreads();
    if (threadIdx.x == 0)
        pool[plane] = (wsum[0] + wsum[1] + wsum[2] + wsum[3]) / (float)HWW;
}

// ---------------------------------------------------------------------------
// Kernel 5: SE MLP -> gate
// ---------------------------------------------------------------------------
__global__ __launch_bounds__(256) void segate_kernel(
    const float* __restrict__ pool, const float* __restrict__ w1,
    const float* __restrict__ w2, float* __restrict__ gate)
{
    __shared__ float hidden[BB * 8];
    int t = threadIdx.x;
    if (t < BB * 8) {
        int b = t / 8, r = t % 8;
        float s = 0.f;
        for (int c = 0; c < CC; ++c) s = fmaf(pool[b * CC + c], w1[r * CC + c], s);
        hidden[t] = fmaxf(s, 0.f);
    }
    __syncthreads();
    for (int idx = t; idx < BB * CC; idx += 256) {
        int b = idx / CC, c = idx % CC;
        float s = 0.f;
        #pragma unroll
        for (int r = 0; r < 8; ++r) s = fmaf(hidden[b * 8 + r], w2[c * 8 + r], s);
        gate[idx] = 1.f / (1.f + expf(-s));
    }
}

// ---------------------------------------------------------------------------
// Kernel 6: out = elu(conv * gate)  (in place on d_out)
// ---------------------------------------------------------------------------
__global__ __launch_bounds__(256) void elu_kernel(
    float* __restrict__ out, const float* __restrict__ gate)
{
    size_t i = (size_t)blockIdx.x * 256 + threadIdx.x;
    int plane = (int)(i / HWW);            // b*128+c
    float x = out[i] * gate[plane];
    out[i] = x > 0.f ? x : expm1f(x);
}

// ---------------------------------------------------------------------------
extern "C" void kernel_launch(void* const* d_in, const int* in_sizes, int n_in,
                              void* d_out, int out_size, void* d_ws, size_t ws_size,
                              hipStream_t stream)
{
    (void)in_sizes; (void)n_in; (void)out_size; (void)ws_size;
    const float* t_feat      = (const float*)d_in[0];
    const float* s_feat      = (const float*)d_in[1];
    const float* directs     = (const float*)d_in[2];
    const int*   image_shape = (const int*)d_in[3];
    const float* q_w  = (const float*)d_in[4];
    const float* q_b  = (const float*)d_in[5];
    const float* k_w  = (const float*)d_in[6];
    const float* k_b  = (const float*)d_in[7];
    const float* ce_w = (const float*)d_in[8];
    const float* ce_b = (const float*)d_in[9];
    const float* fa_w = (const float*)d_in[10];
    const float* fa_b = (const float*)d_in[11];
    const float* redu_w = (const float*)d_in[12];
    const float* se_w1  = (const float*)d_in[13];
    const float* se_w2  = (const float*)d_in[14];

    float* out      = (float*)d_out;
    float* prob_out = out + (size_t)BB * CC * HWW;   // second output region

    float* ws       = (float*)d_ws;
    float* ws_q     = ws;                                  // dead after sim_kernel
    float* ws_k     = ws + (size_t)BB * CRR * HWW;
    float* ws_cost  = ws_q;                                // aliases ws_q (safe: stream-ordered)
    float* ws_fused = ws + 2ull * BB * CRR * HWW;
    float* ws_pool  = ws_fused + (size_t)BB * CC * HWW;
    float* ws_gate  = ws_pool + BB * CC;

    qk_kernel<<<480, 256, 0, stream>>>(t_feat, s_feat, q_w, q_b, k_w, k_b, ws_q, ws_k);
    sim_kernel<<<480, 256, 0, stream>>>(directs, image_shape, ws_q, ws_k, prob_out);
    cost_kernel<<<480, 256, 0, stream>>>(directs, image_shape, ws_k, prob_out, ws_cost);
    fuse_kernel<<<480, 256, 0, stream>>>(t_feat, ce_w, ce_b, fa_w, fa_b, ws_cost, ws_fused);
    conv_kernel<<<dim3(WW / 64, HH, BB), 256, 0, stream>>>(ws_fused, redu_w, out);
    pool_kernel<<<BB * CC, 256, 0, stream>>>(out, ws_pool);
    segate_kernel<<<1, 256, 0, stream>>>(ws_pool, se_w1, se_w2, ws_gate);
    elu_kernel<<<(BB * CC * HWW) / 256, 256, 0, stream>>>(out, ws_gate);
}

// Round 3
// 611.445 us; speedup vs baseline: 5.7759x; 3.0094x over previous
//
#include <hip/hip_runtime.h>
#include <math.h>

#define BB 4
#define CC 128
#define CRR 32
#define DD 24
#define HH 96
#define WW 320
#define HWW (HH*WW)   // 30720

typedef __attribute__((ext_vector_type(8))) short bs8;     // 8 bf16 (4 VGPR)
typedef __attribute__((ext_vector_type(4))) float f32x4;   // MFMA acc
typedef __attribute__((ext_vector_type(4))) int   i32x4;

static __device__ __forceinline__ unsigned short f2bf(float x) {
    unsigned int u = __float_as_uint(x);
    unsigned int r = (u + 0x7fffu + ((u >> 16) & 1u)) >> 16;   // RNE
    return (unsigned short)r;
}

// ---------------------------------------------------------------------------
// Kernel 1: q/k 1x1 conv + l2norm.  One thread per pixel.
// ---------------------------------------------------------------------------
__global__ __launch_bounds__(256) void qk_kernel(
    const float* __restrict__ t_feat, const float* __restrict__ s_feat,
    const float* __restrict__ q_w, const float* __restrict__ q_b,
    const float* __restrict__ k_w, const float* __restrict__ k_b,
    float* __restrict__ ws_q, float* __restrict__ ws_k)
{
    int p = blockIdx.x * 256 + threadIdx.x;        // 0..122879
    int b = p / HWW, rem = p % HWW;

    float accq[CRR], acck[CRR];
    #pragma unroll
    for (int o = 0; o < CRR; ++o) { accq[o] = q_b[o]; acck[o] = k_b[o]; }

    const float* tp = t_feat + (size_t)b * CC * HWW + rem;
    const float* sp = s_feat + (size_t)b * CC * HWW + rem;

    #pragma unroll 4
    for (int c = 0; c < CC; ++c) {
        float tv = tp[(size_t)c * HWW];
        float sv = sp[(size_t)c * HWW];
        #pragma unroll
        for (int o = 0; o < CRR; ++o) {
            accq[o] = fmaf(tv, q_w[o * CC + c], accq[o]);
            acck[o] = fmaf(sv, k_w[o * CC + c], acck[o]);
        }
    }
    float nq = 0.f, nk = 0.f;
    #pragma unroll
    for (int o = 0; o < CRR; ++o) { nq = fmaf(accq[o], accq[o], nq); nk = fmaf(acck[o], acck[o], nk); }
    float invq = 1.f / fmaxf(sqrtf(nq), 1e-12f);
    float invk = 1.f / fmaxf(sqrtf(nk), 1e-12f);
    #pragma unroll
    for (int o = 0; o < CRR; ++o) {
        ws_q[((size_t)b * CRR + o) * HWW + rem] = accq[o] * invq;
        ws_k[((size_t)b * CRR + o) * HWW + rem] = acck[o] * invk;
    }
}

// ---------------------------------------------------------------------------
// Kernel 2a: sim = q . warp(k)  -> softmax over d -> prob (to d_out)
// ---------------------------------------------------------------------------
__global__ __launch_bounds__(256) void sim_kernel(
    const float* __restrict__ directs, const int* __restrict__ image_shape,
    const float* __restrict__ ws_q, const float* __restrict__ ws_k,
    float* __restrict__ prob_out)
{
    int p = blockIdx.x * 256 + threadIdx.x;
    int b = p / HWW, rem = p % HWW;
    int h = rem / WW, w = rem % WW;

    float rel = 640.0f / (float)image_shape[3];
    float fscale = rel * directs[b] * (float)(WW - 1);

    float q[CRR];
    #pragma unroll
    for (int c = 0; c < CRR; ++c) q[c] = ws_q[((size_t)b * CRR + c) * HWW + rem];

    const float* kbase = ws_k + (size_t)b * CRR * HWW + h * WW;

    float sim[DD];
    #pragma unroll 2
    for (int d = 0; d < DD; ++d) {
        float disp = 0.3f * (float)d / 23.0f;
        float fx = fminf(fmaxf((float)w + disp * fscale, 0.f), (float)(WW - 1));
        int ix0 = (int)floorf(fx);
        int ix1 = min(ix0 + 1, WW - 1);
        float w1 = fx - (float)ix0;
        float s = 0.f;
        #pragma unroll
        for (int c = 0; c < CRR; ++c) {
            float k0 = kbase[c * HWW + ix0];
            float k1 = kbase[c * HWW + ix1];
            s = fmaf(q[c], fmaf(w1, k1 - k0, k0), s);
        }
        sim[d] = s;
    }
    float m = sim[0];
    #pragma unroll
    for (int d = 1; d < DD; ++d) m = fmaxf(m, sim[d]);
    float sum = 0.f;
    #pragma unroll
    for (int d = 0; d < DD; ++d) { sim[d] = expf(sim[d] - m); sum += sim[d]; }
    float inv = 1.f / sum;
    #pragma unroll
    for (int d = 0; d < DD; ++d)
        prob_out[((size_t)b * DD + d) * HWW + rem] = sim[d] * inv;
}

// ---------------------------------------------------------------------------
// Kernel 2b: cost[c] = sum_d prob_d * warp(k)[c]  -> ws_cost planes
// ---------------------------------------------------------------------------
__global__ __launch_bounds__(256) void cost_kernel(
    const float* __restrict__ directs, const int* __restrict__ image_shape,
    const float* __restrict__ ws_k, const float* __restrict__ prob_out,
    float* __restrict__ ws_cost)
{
    int p = blockIdx.x * 256 + threadIdx.x;
    int b = p / HWW, rem = p % HWW;
    int h = rem / WW, w = rem % WW;

    float rel = 640.0f / (float)image_shape[3];
    float fscale = rel * directs[b] * (float)(WW - 1);

    const float* kbase = ws_k + (size_t)b * CRR * HWW + h * WW;

    float cost[CRR];
    #pragma unroll
    for (int c = 0; c < CRR; ++c) cost[c] = 0.f;

    #pragma unroll 2
    for (int d = 0; d < DD; ++d) {
        float pr = prob_out[((size_t)b * DD + d) * HWW + rem];
        float disp = 0.3f * (float)d / 23.0f;
        float fx = fminf(fmaxf((float)w + disp * fscale, 0.f), (float)(WW - 1));
        int ix0 = (int)floorf(fx);
        int ix1 = min(ix0 + 1, WW - 1);
        float w1 = fx - (float)ix0;
        #pragma unroll
        for (int c = 0; c < CRR; ++c) {
            float k0 = kbase[c * HWW + ix0];
            float k1 = kbase[c * HWW + ix1];
            cost[c] = fmaf(pr, fmaf(w1, k1 - k0, k0), cost[c]);
        }
    }
    #pragma unroll
    for (int c = 0; c < CRR; ++c)
        ws_cost[((size_t)b * CRR + c) * HWW + rem] = cost[c];
}

// ---------------------------------------------------------------------------
// Kernel 2c: cost-expand (1x1, 32->128) + alpha (sigmoid) + fuse -> ws_fused
// ---------------------------------------------------------------------------
__global__ __launch_bounds__(256) void fuse_kernel(
    const float* __restrict__ t_feat,
    const float* __restrict__ ce_w, const float* __restrict__ ce_b,
    const float* __restrict__ fa_w, const float* __restrict__ fa_b,
    const float* __restrict__ ws_cost, float* __restrict__ ws_fused)
{
    int p = blockIdx.x * 256 + threadIdx.x;
    int b = p / HWW, rem = p % HWW;

    float cost[CRR];
    #pragma unroll
    for (int c = 0; c < CRR; ++c) cost[c] = ws_cost[((size_t)b * CRR + c) * HWW + rem];

    const float* tp = t_feat + (size_t)b * CC * HWW + rem;
    float at = 0.f, ac = 0.f;
    #pragma unroll 1
    for (int oc = 0; oc < CC; ++oc) {
        float ce = ce_b[oc];
        #pragma unroll
        for (int c = 0; c < CRR; ++c) ce = fmaf(cost[c], ce_w[oc * CRR + c], ce);
        at = fmaf(fa_w[oc], tp[(size_t)oc * HWW], at);
        ac = fmaf(fa_w[CC + oc], ce, ac);
    }
    float alpha = 1.f / (1.f + expf(-(at + ac + fa_b[0])));
    #pragma unroll 1
    for (int oc = 0; oc < CC; ++oc) {
        float ce = ce_b[oc];
        #pragma unroll
        for (int c = 0; c < CRR; ++c) ce = fmaf(cost[c], ce_w[oc * CRR + c], ce);
        float tv = tp[(size_t)oc * HWW];
        ws_fused[((size_t)b * CC + oc) * HWW + rem] = alpha * tv + (1.f - alpha) * ce;
    }
}

// ---------------------------------------------------------------------------
// Weight repack: redu_w [O][I][3][3] f32 -> bf16 B-fragments
// wb[(((tap*4+kc)*8 + ocf)*64 + lane)*8 + j] = w[ocf*16+(lane&15)][kc*32+(lane>>4)*8+j][tap]
// ---------------------------------------------------------------------------
__global__ __launch_bounds__(256) void repack_w_kernel(
    const float* __restrict__ redu_w, unsigned short* __restrict__ wb)
{
    int idx = blockIdx.x * 256 + threadIdx.x;   // < 147456
    int j    = idx & 7;
    int l    = (idx >> 3) & 63;
    int rest = idx >> 9;
    int ocf  = rest & 7;
    int kc   = (rest >> 3) & 3;
    int tap  = rest >> 5;            // 0..8
    int oc = ocf * 16 + (l & 15);
    int ic = kc * 32 + (l >> 4) * 8 + j;
    wb[idx] = f2bf(redu_w[(size_t)(oc * CC + ic) * 9 + tap]);
}

// ---------------------------------------------------------------------------
// Kernel 3: 3x3 reflect-pad conv (128->128) via bf16 MFMA implicit GEMM.
// Block = (wtile of 64 px, h, b), 4 waves; wave w owns oc [32w, 32w+32).
// A: LDS slab 3 rows x 66 cols x 128 ch bf16, XOR-swizzled 16B slots.
// B: repacked global fragments (L1/L2-resident).
// ---------------------------------------------------------------------------
__global__ __launch_bounds__(256) void conv_mfma_kernel(
    const float* __restrict__ ws_fused, const unsigned short* __restrict__ wb,
    float* __restrict__ out_conv)
{
    __shared__ __align__(16) unsigned char lds[3 * 66 * 256];
    int tid  = threadIdx.x;
    int lane = tid & 63;
    int wid  = __builtin_amdgcn_readfirstlane(tid >> 6);
    int w0 = blockIdx.x * 64;
    int h  = blockIdx.y;
    int b  = blockIdx.z;

    const float* fb = ws_fused + (size_t)b * CC * HWW;

    // stage: 3 rows x 66 cols x 16 slots (8 ch each) = 3168 16B chunks
    for (int ci = tid; ci < 3 * 66 * 16; ci += 256) {
        int col  = ci % 66;
        int rs   = ci / 66;
        int slot = rs & 15;
        int row  = rs >> 4;
        int grow = h - 1 + row; grow = grow < 0 ? 1 : (grow > HH - 1 ? HH - 2 : grow);
        int gcol = w0 - 1 + col; gcol = gcol < 0 ? -gcol : (gcol > WW - 1 ? 2 * (WW - 1) - gcol : gcol);
        const float* src = fb + (size_t)(slot * 8) * HWW + grow * WW + gcol;
        i32x4 u;
        #pragma unroll
        for (int j = 0; j < 4; ++j) {
            unsigned short lo = f2bf(src[(size_t)(2 * j) * HWW]);
            unsigned short hi = f2bf(src[(size_t)(2 * j + 1) * HWW]);
            u[j] = (int)((unsigned int)lo | ((unsigned int)hi << 16));
        }
        int addr = (row * 66 + col) * 256 + ((slot ^ (col & 7)) << 4);
        *(i32x4*)(lds + addr) = u;
    }
    __syncthreads();

    f32x4 acc[4][2];
    #pragma unroll
    for (int pf = 0; pf < 4; ++pf)
        #pragma unroll
        for (int of = 0; of < 2; ++of)
            acc[pf][of] = (f32x4){0.f, 0.f, 0.f, 0.f};

    int l15 = lane & 15, l4 = lane >> 4;
    const bs8* wbp = (const bs8*)wb;

    #pragma unroll 1
    for (int tap = 0; tap < 9; ++tap) {
        int ky = tap / 3, kx = tap % 3;
        #pragma unroll
        for (int kc = 0; kc < 4; ++kc) {
            bs8 a[4];
            #pragma unroll
            for (int pf = 0; pf < 4; ++pf) {
                int colt = pf * 16 + l15 + kx;                  // 0..65
                int addr = (ky * 66 + colt) * 256 + (((kc * 4 + l4) ^ (colt & 7)) << 4);
                a[pf] = *(const bs8*)(lds + addr);
            }
            bs8 bf[2];
            #pragma unroll
            for (int of = 0; of < 2; ++of)
                bf[of] = wbp[((tap * 4 + kc) * 8 + wid * 2 + of) * 64 + lane];
            #pragma unroll
            for (int pf = 0; pf < 4; ++pf)
                #pragma unroll
                for (int of = 0; of < 2; ++of)
                    acc[pf][of] = __builtin_amdgcn_mfma_f32_16x16x32_bf16(
                        a[pf], bf[of], acc[pf][of], 0, 0, 0);
        }
    }

    // C/D layout: col = lane&15 (oc), row = (lane>>4)*4 + reg (pixel)
    #pragma unroll
    for (int pf = 0; pf < 4; ++pf)
        #pragma unroll
        for (int of = 0; of < 2; ++of) {
            int oc = wid * 32 + of * 16 + l15;
            #pragma unroll
            for (int r = 0; r < 4; ++r) {
                int px = pf * 16 + l4 * 4 + r;
                out_conv[((size_t)b * CC + oc) * HWW + h * WW + w0 + px] = acc[pf][of][r];
            }
        }
}

// ---------------------------------------------------------------------------
// Kernel 4: per-(b,c) plane mean
// ---------------------------------------------------------------------------
__global__ __launch_bounds__(256) void pool_kernel(
    const float* __restrict__ conv, float* __restrict__ pool)
{
    int plane = blockIdx.x;                // 0..511
    const float* p = conv + (size_t)plane * HWW;
    float s = 0.f;
    for (int i = threadIdx.x; i < HWW; i += 256) s += p[i];
    #pragma unroll
    for (int off = 32; off; off >>= 1) s += __shfl_down(s, off);
    __shared__ float wsum[4];
    if ((threadIdx.x & 63) == 0) wsum[threadIdx.x >> 6] = s;
    __syncthreads();
    if (threadIdx.x == 0)
        pool[plane] = (wsum[0] + wsum[1] + wsum[2] + wsum[3]) / (float)HWW;
}

// ---------------------------------------------------------------------------
// Kernel 5: SE MLP -> gate
// ---------------------------------------------------------------------------
__global__ __launch_bounds__(256) void segate_kernel(
    const float* __restrict__ pool, const float* __restrict__ w1,
    const float* __restrict__ w2, float* __restrict__ gate)
{
    __shared__ float hidden[BB * 8];
    int t = threadIdx.x;
    if (t < BB * 8) {
        int b = t / 8, r = t % 8;
        float s = 0.f;
        for (int c = 0; c < CC; ++c) s = fmaf(pool[b * CC + c], w1[r * CC + c], s);
        hidden[t] = fmaxf(s, 0.f);
    }
    __syncthreads();
    for (int idx = t; idx < BB * CC; idx += 256) {
        int b = idx / CC, c = idx % CC;
        float s = 0.f;
        #pragma unroll
        for (int r = 0; r < 8; ++r) s = fmaf(hidden[b * 8 + r], w2[c * 8 + r], s);
        gate[idx] = 1.f / (1.f + expf(-s));
    }
}

// ---------------------------------------------------------------------------
// Kernel 6: out = elu(conv * gate)  (in place on d_out)
// ---------------------------------------------------------------------------
__global__ __launch_bounds__(256) void elu_kernel(
    float* __restrict__ out, const float* __restrict__ gate)
{
    size_t i = (size_t)blockIdx.x * 256 + threadIdx.x;
    int plane = (int)(i / HWW);            // b*128+c
    float x = out[i] * gate[plane];
    out[i] = x > 0.f ? x : expm1f(x);
}

// ---------------------------------------------------------------------------
extern "C" void kernel_launch(void* const* d_in, const int* in_sizes, int n_in,
                              void* d_out, int out_size, void* d_ws, size_t ws_size,
                              hipStream_t stream)
{
    (void)in_sizes; (void)n_in; (void)out_size; (void)ws_size;
    const float* t_feat      = (const float*)d_in[0];
    const float* s_feat      = (const float*)d_in[1];
    const float* directs     = (const float*)d_in[2];
    const int*   image_shape = (const int*)d_in[3];
    const float* q_w  = (const float*)d_in[4];
    const float* q_b  = (const float*)d_in[5];
    const float* k_w  = (const float*)d_in[6];
    const float* k_b  = (const float*)d_in[7];
    const float* ce_w = (const float*)d_in[8];
    const float* ce_b = (const float*)d_in[9];
    const float* fa_w = (const float*)d_in[10];
    const float* fa_b = (const float*)d_in[11];
    const float* redu_w = (const float*)d_in[12];
    const float* se_w1  = (const float*)d_in[13];
    const float* se_w2  = (const float*)d_in[14];

    float* out      = (float*)d_out;
    float* prob_out = out + (size_t)BB * CC * HWW;   // second output region

    float* ws       = (float*)d_ws;
    float* ws_q     = ws;                                  // dead after sim_kernel
    float* ws_k     = ws + (size_t)BB * CRR * HWW;         // dead after cost_kernel
    float* ws_cost  = ws_q;                                // aliases ws_q
    float* ws_fused = ws + 2ull * BB * CRR * HWW;
    float* ws_pool  = ws_fused + (size_t)BB * CC * HWW;
    float* ws_gate  = ws_pool + BB * CC;
    unsigned short* ws_wb = (unsigned short*)ws_k;         // aliases dead ws_k (295 KB)

    qk_kernel<<<480, 256, 0, stream>>>(t_feat, s_feat, q_w, q_b, k_w, k_b, ws_q, ws_k);
    sim_kernel<<<480, 256, 0, stream>>>(directs, image_shape, ws_q, ws_k, prob_out);
    cost_kernel<<<480, 256, 0, stream>>>(directs, image_shape, ws_k, prob_out, ws_cost);
    fuse_kernel<<<480, 256, 0, stream>>>(t_feat, ce_w, ce_b, fa_w, fa_b, ws_cost, ws_fused);
    repack_w_kernel<<<576, 256, 0, stream>>>(redu_w, ws_wb);
    conv_mfma_kernel<<<dim3(WW / 64, HH, BB), 256, 0, stream>>>(ws_fused, ws_wb, out);
    pool_kernel<<<BB * CC, 256, 0, stream>>>(out, ws_pool);
    segate_kernel<<<1, 256, 0, stream>>>(ws_pool, se_w1, se_w2, ws_gate);
    elu_kernel<<<(BB * CC * HWW) / 256, 256, 0, stream>>>(out, ws_gate);
}

// Round 4
// 461.107 us; speedup vs baseline: 7.6590x; 1.3260x over previous
//
#include <hip/hip_runtime.h>
#include <math.h>

#define BB 4
#define CC 128
#define CRR 32
#define DD 24
#define HH 96
#define WW 320
#define HWW (HH*WW)   // 30720

typedef __attribute__((ext_vector_type(8))) short bs8;     // 8 bf16 (4 VGPR)
typedef __attribute__((ext_vector_type(4))) float f32x4;   // MFMA acc
typedef __attribute__((ext_vector_type(4))) int   i32x4;

static __device__ __forceinline__ unsigned short f2bf(float x) {
    unsigned int u = __float_as_uint(x);
    unsigned int r = (u + 0x7fffu + ((u >> 16) & 1u)) >> 16;   // RNE
    return (unsigned short)r;
}

// ---------------------------------------------------------------------------
// Repack q_w/k_w -> bf16 B-fragments.
// wqk[((g*2+ofh)*4+kc)*64*8 + l*8 + j] = w_g[(ofh*16+(l&15))*128 + kc*32+(l>>4)*8+j]
// ---------------------------------------------------------------------------
__global__ __launch_bounds__(256) void repack_qk_kernel(
    const float* __restrict__ q_w, const float* __restrict__ k_w,
    unsigned short* __restrict__ wqk)
{
    int idx = blockIdx.x * 256 + threadIdx.x;    // < 8192
    int j   = idx & 7;
    int l   = (idx >> 3) & 63;
    int kc  = (idx >> 9) & 3;
    int ofh = (idx >> 11) & 1;
    int g   = idx >> 12;
    const float* w = g ? k_w : q_w;
    int oc = ofh * 16 + (l & 15);
    int ic = kc * 32 + (l >> 4) * 8 + j;
    wqk[idx] = f2bf(w[oc * CC + ic]);
}

// ---------------------------------------------------------------------------
// Kernel 1: q/k 1x1 conv + bias + l2norm via bf16 MFMA.
// Block = 64 flat pixels, 4 waves: wave = (g, ofh); g: 0=q(t_feat) 1=k(s_feat).
// A tiles (t,s) staged bf16 in swizzled LDS; epilogue reuses LDS for norm.
// ---------------------------------------------------------------------------
__global__ __launch_bounds__(256) void qk_mfma_kernel(
    const float* __restrict__ t_feat, const float* __restrict__ s_feat,
    const unsigned short* __restrict__ wqk,
    const float* __restrict__ q_b, const float* __restrict__ k_b,
    float* __restrict__ ws_q, float* __restrict__ ws_k)
{
    __shared__ __align__(16) unsigned char lds[2 * 64 * 16 * 16];   // 32 KB
    int tid  = threadIdx.x;
    int lane = tid & 63;
    int wid  = __builtin_amdgcn_readfirstlane(tid >> 6);
    int g = wid >> 1, ofh = wid & 1;
    int p0 = blockIdx.x * 64;
    int b = p0 / HWW, rem0 = p0 % HWW;

    // stage both 64px x 128ch tiles as bf16, 16B slots, slot ^= px&7
    for (int ci = tid; ci < 2 * 64 * 16; ci += 256) {
        int px   = ci & 63;
        int slot = (ci >> 6) & 15;
        int m    = ci >> 10;
        const float* src = (m ? s_feat : t_feat)
                         + (size_t)b * CC * HWW + (size_t)(slot * 8) * HWW + rem0 + px;
        i32x4 u;
        #pragma unroll
        for (int j = 0; j < 4; ++j) {
            unsigned short lo = f2bf(src[(size_t)(2 * j) * HWW]);
            unsigned short hi = f2bf(src[(size_t)(2 * j + 1) * HWW]);
            u[j] = (int)((unsigned int)lo | ((unsigned int)hi << 16));
        }
        int addr = m * 16384 + px * 256 + ((slot ^ (px & 7)) << 4);
        *(i32x4*)(lds + addr) = u;
    }
    __syncthreads();

    int l15 = lane & 15, l4 = lane >> 4;
    f32x4 acc[4];
    #pragma unroll
    for (int pf = 0; pf < 4; ++pf) acc[pf] = (f32x4){0.f, 0.f, 0.f, 0.f};

    const bs8* wp = (const bs8*)wqk + (size_t)(g * 2 + ofh) * 4 * 64;
    #pragma unroll
    for (int kc = 0; kc < 4; ++kc) {
        bs8 bf = wp[kc * 64 + lane];
        #pragma unroll
        for (int pf = 0; pf < 4; ++pf) {
            int addr = g * 16384 + (pf * 16 + l15) * 256 + (((kc * 4 + l4) ^ (l15 & 7)) << 4);
            bs8 a = *(const bs8*)(lds + addr);
            acc[pf] = __builtin_amdgcn_mfma_f32_16x16x32_bf16(a, bf, acc[pf], 0, 0, 0);
        }
    }
    __syncthreads();    // A tiles dead; reuse LDS as f32 [2][64][33]

    float* fl = (float*)lds;
    float bias = (g ? k_b : q_b)[ofh * 16 + l15];
    #pragma unroll
    for (int pf = 0; pf < 4; ++pf)
        #pragma unroll
        for (int r = 0; r < 4; ++r) {
            int px = pf * 16 + l4 * 4 + r;
            fl[(g * 64 + px) * 33 + ofh * 16 + l15] = acc[pf][r] + bias;
        }
    __syncthreads();

    if (tid < 128) {
        int gg = tid >> 6, px = tid & 63;
        const float* row = fl + (gg * 64 + px) * 33;
        float n = 0.f;
        #pragma unroll
        for (int oc = 0; oc < CRR; ++oc) n = fmaf(row[oc], row[oc], n);
        float inv = 1.f / fmaxf(sqrtf(n), 1e-12f);
        float* dst = (gg ? ws_k : ws_q) + (size_t)b * CRR * HWW + rem0 + px;
        #pragma unroll
        for (int oc = 0; oc < CRR; ++oc)
            dst[(size_t)oc * HWW] = row[oc] * inv;
    }
}

// ---------------------------------------------------------------------------
// Kernel 2: sim + softmax -> prob (d_out)  AND  cost -> ws_cost, fused.
// One thread per pixel.  q[] dies before cost[] is live: ~90 VGPR peak.
// ---------------------------------------------------------------------------
__global__ __launch_bounds__(256) void simcost_kernel(
    const float* __restrict__ directs, const int* __restrict__ image_shape,
    const float* __restrict__ ws_q, const float* __restrict__ ws_k,
    float* __restrict__ prob_out, float* __restrict__ ws_cost)
{
    int p = blockIdx.x * 256 + threadIdx.x;
    int b = p / HWW, rem = p % HWW;
    int h = rem / WW, w = rem % WW;

    float rel = 640.0f / (float)image_shape[3];
    float fscale = rel * directs[b] * (float)(WW - 1);

    const float* kbase = ws_k + (size_t)b * CRR * HWW + h * WW;

    float sim[DD];
    {
        float q[CRR];
        #pragma unroll
        for (int c = 0; c < CRR; ++c) q[c] = ws_q[((size_t)b * CRR + c) * HWW + rem];
        #pragma unroll 2
        for (int d = 0; d < DD; ++d) {
            float disp = 0.3f * (float)d / 23.0f;
            float fx = fminf(fmaxf((float)w + disp * fscale, 0.f), (float)(WW - 1));
            int ix0 = (int)floorf(fx);
            int ix1 = min(ix0 + 1, WW - 1);
            float w1 = fx - (float)ix0;
            float s = 0.f;
            #pragma unroll
            for (int c = 0; c < CRR; ++c) {
                float k0 = kbase[c * HWW + ix0];
                float k1 = kbase[c * HWW + ix1];
                s = fmaf(q[c], fmaf(w1, k1 - k0, k0), s);
            }
            sim[d] = s;
        }
    }
    float m = sim[0];
    #pragma unroll
    for (int d = 1; d < DD; ++d) m = fmaxf(m, sim[d]);
    float sum = 0.f;
    #pragma unroll
    for (int d = 0; d < DD; ++d) { sim[d] = expf(sim[d] - m); sum += sim[d]; }
    float inv = 1.f / sum;
    #pragma unroll
    for (int d = 0; d < DD; ++d) {
        sim[d] *= inv;                                    // prob
        prob_out[((size_t)b * DD + d) * HWW + rem] = sim[d];
    }

    float cost[CRR];
    #pragma unroll
    for (int c = 0; c < CRR; ++c) cost[c] = 0.f;
    #pragma unroll 2
    for (int d = 0; d < DD; ++d) {
        float pr = sim[d];
        float disp = 0.3f * (float)d / 23.0f;
        float fx = fminf(fmaxf((float)w + disp * fscale, 0.f), (float)(WW - 1));
        int ix0 = (int)floorf(fx);
        int ix1 = min(ix0 + 1, WW - 1);
        float w1 = fx - (float)ix0;
        #pragma unroll
        for (int c = 0; c < CRR; ++c) {
            float k0 = kbase[c * HWW + ix0];
            float k1 = kbase[c * HWW + ix1];
            cost[c] = fmaf(pr, fmaf(w1, k1 - k0, k0), cost[c]);
        }
    }
    #pragma unroll
    for (int c = 0; c < CRR; ++c)
        ws_cost[((size_t)b * CRR + c) * HWW + rem] = cost[c];
}

// ---------------------------------------------------------------------------
// Kernel 2c: cost-expand (1x1, 32->128) + alpha (sigmoid) + fuse -> ws_fused
// ---------------------------------------------------------------------------
__global__ __launch_bounds__(256) void fuse_kernel(
    const float* __restrict__ t_feat,
    const float* __restrict__ ce_w, const float* __restrict__ ce_b,
    const float* __restrict__ fa_w, const float* __restrict__ fa_b,
    const float* __restrict__ ws_cost, float* __restrict__ ws_fused)
{
    int p = blockIdx.x * 256 + threadIdx.x;
    int b = p / HWW, rem = p % HWW;

    float cost[CRR];
    #pragma unroll
    for (int c = 0; c < CRR; ++c) cost[c] = ws_cost[((size_t)b * CRR + c) * HWW + rem];

    const float* tp = t_feat + (size_t)b * CC * HWW + rem;
    float at = 0.f, ac = 0.f;
    #pragma unroll 1
    for (int oc = 0; oc < CC; ++oc) {
        float ce = ce_b[oc];
        #pragma unroll
        for (int c = 0; c < CRR; ++c) ce = fmaf(cost[c], ce_w[oc * CRR + c], ce);
        at = fmaf(fa_w[oc], tp[(size_t)oc * HWW], at);
        ac = fmaf(fa_w[CC + oc], ce, ac);
    }
    float alpha = 1.f / (1.f + expf(-(at + ac + fa_b[0])));
    #pragma unroll 1
    for (int oc = 0; oc < CC; ++oc) {
        float ce = ce_b[oc];
        #pragma unroll
        for (int c = 0; c < CRR; ++c) ce = fmaf(cost[c], ce_w[oc * CRR + c], ce);
        float tv = tp[(size_t)oc * HWW];
        ws_fused[((size_t)b * CC + oc) * HWW + rem] = alpha * tv + (1.f - alpha) * ce;
    }
}

// ---------------------------------------------------------------------------
// Weight repack: redu_w [O][I][3][3] f32 -> bf16 B-fragments
// ---------------------------------------------------------------------------
__global__ __launch_bounds__(256) void repack_w_kernel(
    const float* __restrict__ redu_w, unsigned short* __restrict__ wb)
{
    int idx = blockIdx.x * 256 + threadIdx.x;   // < 147456
    int j    = idx & 7;
    int l    = (idx >> 3) & 63;
    int rest = idx >> 9;
    int ocf  = rest & 7;
    int kc   = (rest >> 3) & 3;
    int tap  = rest >> 5;            // 0..8
    int oc = ocf * 16 + (l & 15);
    int ic = kc * 32 + (l >> 4) * 8 + j;
    wb[idx] = f2bf(redu_w[(size_t)(oc * CC + ic) * 9 + tap]);
}

// ---------------------------------------------------------------------------
// Kernel 3: 3x3 reflect-pad conv (128->128) via bf16 MFMA implicit GEMM.
// ---------------------------------------------------------------------------
__global__ __launch_bounds__(256) void conv_mfma_kernel(
    const float* __restrict__ ws_fused, const unsigned short* __restrict__ wb,
    float* __restrict__ out_conv)
{
    __shared__ __align__(16) unsigned char lds[3 * 66 * 256];
    int tid  = threadIdx.x;
    int lane = tid & 63;
    int wid  = __builtin_amdgcn_readfirstlane(tid >> 6);
    int w0 = blockIdx.x * 64;
    int h  = blockIdx.y;
    int b  = blockIdx.z;

    const float* fb = ws_fused + (size_t)b * CC * HWW;

    for (int ci = tid; ci < 3 * 66 * 16; ci += 256) {
        int col  = ci % 66;
        int rs   = ci / 66;
        int slot = rs & 15;
        int row  = rs >> 4;
        int grow = h - 1 + row; grow = grow < 0 ? 1 : (grow > HH - 1 ? HH - 2 : grow);
        int gcol = w0 - 1 + col; gcol = gcol < 0 ? -gcol : (gcol > WW - 1 ? 2 * (WW - 1) - gcol : gcol);
        const float* src = fb + (size_t)(slot * 8) * HWW + grow * WW + gcol;
        i32x4 u;
        #pragma unroll
        for (int j = 0; j < 4; ++j) {
            unsigned short lo = f2bf(src[(size_t)(2 * j) * HWW]);
            unsigned short hi = f2bf(src[(size_t)(2 * j + 1) * HWW]);
            u[j] = (int)((unsigned int)lo | ((unsigned int)hi << 16));
        }
        int addr = (row * 66 + col) * 256 + ((slot ^ (col & 7)) << 4);
        *(i32x4*)(lds + addr) = u;
    }
    __syncthreads();

    f32x4 acc[4][2];
    #pragma unroll
    for (int pf = 0; pf < 4; ++pf)
        #pragma unroll
        for (int of = 0; of < 2; ++of)
            acc[pf][of] = (f32x4){0.f, 0.f, 0.f, 0.f};

    int l15 = lane & 15, l4 = lane >> 4;
    const bs8* wbp = (const bs8*)wb;

    #pragma unroll 1
    for (int tap = 0; tap < 9; ++tap) {
        int ky = tap / 3, kx = tap % 3;
        #pragma unroll
        for (int kc = 0; kc < 4; ++kc) {
            bs8 a[4];
            #pragma unroll
            for (int pf = 0; pf < 4; ++pf) {
                int colt = pf * 16 + l15 + kx;                  // 0..65
                int addr = (ky * 66 + colt) * 256 + (((kc * 4 + l4) ^ (colt & 7)) << 4);
                a[pf] = *(const bs8*)(lds + addr);
            }
            bs8 bf[2];
            #pragma unroll
            for (int of = 0; of < 2; ++of)
                bf[of] = wbp[((tap * 4 + kc) * 8 + wid * 2 + of) * 64 + lane];
            #pragma unroll
            for (int pf = 0; pf < 4; ++pf)
                #pragma unroll
                for (int of = 0; of < 2; ++of)
                    acc[pf][of] = __builtin_amdgcn_mfma_f32_16x16x32_bf16(
                        a[pf], bf[of], acc[pf][of], 0, 0, 0);
        }
    }

    #pragma unroll
    for (int pf = 0; pf < 4; ++pf)
        #pragma unroll
        for (int of = 0; of < 2; ++of) {
            int oc = wid * 32 + of * 16 + l15;
            #pragma unroll
            for (int r = 0; r < 4; ++r) {
                int px = pf * 16 + l4 * 4 + r;
                out_conv[((size_t)b * CC + oc) * HWW + h * WW + w0 + px] = acc[pf][of][r];
            }
        }
}

// ---------------------------------------------------------------------------
// Kernel 4: per-(b,c) plane mean
// ---------------------------------------------------------------------------
__global__ __launch_bounds__(256) void pool_kernel(
    const float* __restrict__ conv, float* __restrict__ pool)
{
    int plane = blockIdx.x;                // 0..511
    const float* p = conv + (size_t)plane * HWW;
    float s = 0.f;
    for (int i = threadIdx.x; i < HWW; i += 256) s += p[i];
    #pragma unroll
    for (int off = 32; off; off >>= 1) s += __shfl_down(s, off);
    __shared__ float wsum[4];
    if ((threadIdx.x & 63) == 0) wsum[threadIdx.x >> 6] = s;
    __syncthreads();
    if (threadIdx.x == 0)
        pool[plane] = (wsum[0] + wsum[1] + wsum[2] + wsum[3]) / (float)HWW;
}

// ---------------------------------------------------------------------------
// Kernel 5: SE MLP -> gate
// ---------------------------------------------------------------------------
__global__ __launch_bounds__(256) void segate_kernel(
    const float* __restrict__ pool, const float* __restrict__ w1,
    const float* __restrict__ w2, float* __restrict__ gate)
{
    __shared__ float hidden[BB * 8];
    int t = threadIdx.x;
    if (t < BB * 8) {
        int b = t / 8, r = t % 8;
        float s = 0.f;
        for (int c = 0; c < CC; ++c) s = fmaf(pool[b * CC + c], w1[r * CC + c], s);
        hidden[t] = fmaxf(s, 0.f);
    }
    __syncthreads();
    for (int idx = t; idx < BB * CC; idx += 256) {
        int b = idx / CC, c = idx % CC;
        float s = 0.f;
        #pragma unroll
        for (int r = 0; r < 8; ++r) s = fmaf(hidden[b * 8 + r], w2[c * 8 + r], s);
        gate[idx] = 1.f / (1.f + expf(-s));
    }
}

// ---------------------------------------------------------------------------
// Kernel 6: out = elu(conv * gate)  (in place on d_out)
// ---------------------------------------------------------------------------
__global__ __launch_bounds__(256) void elu_kernel(
    float* __restrict__ out, const float* __restrict__ gate)
{
    size_t i = (size_t)blockIdx.x * 256 + threadIdx.x;
    int plane = (int)(i / HWW);            // b*128+c
    float x = out[i] * gate[plane];
    out[i] = x > 0.f ? x : expm1f(x);
}

// ---------------------------------------------------------------------------
extern "C" void kernel_launch(void* const* d_in, const int* in_sizes, int n_in,
                              void* d_out, int out_size, void* d_ws, size_t ws_size,
                              hipStream_t stream)
{
    (void)in_sizes; (void)n_in; (void)out_size; (void)ws_size;
    const float* t_feat      = (const float*)d_in[0];
    const float* s_feat      = (const float*)d_in[1];
    const float* directs     = (const float*)d_in[2];
    const int*   image_shape = (const int*)d_in[3];
    const float* q_w  = (const float*)d_in[4];
    const float* q_b  = (const float*)d_in[5];
    const float* k_w  = (const float*)d_in[6];
    const float* k_b  = (const float*)d_in[7];
    const float* ce_w = (const float*)d_in[8];
    const float* ce_b = (const float*)d_in[9];
    const float* fa_w = (const float*)d_in[10];
    const float* fa_b = (const float*)d_in[11];
    const float* redu_w = (const float*)d_in[12];
    const float* se_w1  = (const float*)d_in[13];
    const float* se_w2  = (const float*)d_in[14];

    float* out      = (float*)d_out;
    float* prob_out = out + (size_t)BB * CC * HWW;   // second output region

    float* ws       = (float*)d_ws;
    float* ws_q     = ws;                                  // dead after simcost
    float* ws_k     = ws + (size_t)BB * CRR * HWW;         // dead after simcost
    float* ws_cost  = ws_q;                                // aliases ws_q
    float* ws_fused = ws + 2ull * BB * CRR * HWW;
    float* ws_pool  = ws_fused + (size_t)BB * CC * HWW;
    float* ws_gate  = ws_pool + BB * CC;
    unsigned short* ws_wb  = (unsigned short*)ws_k;        // redu frags: alias dead ws_k
    unsigned short* ws_wqk = (unsigned short*)ws_fused;    // qk frags: alias pre-fuse ws_fused

    repack_qk_kernel<<<32, 256, 0, stream>>>(q_w, k_w, ws_wqk);
    qk_mfma_kernel<<<BB * HWW / 64, 256, 0, stream>>>(t_feat, s_feat, ws_wqk,
                                                      q_b, k_b, ws_q, ws_k);
    simcost_kernel<<<480, 256, 0, stream>>>(directs, image_shape, ws_q, ws_k,
                                            prob_out, ws_cost);
    fuse_kernel<<<480, 256, 0, stream>>>(t_feat, ce_w, ce_b, fa_w, fa_b, ws_cost, ws_fused);
    repack_w_kernel<<<576, 256, 0, stream>>>(redu_w, ws_wb);
    conv_mfma_kernel<<<dim3(WW / 64, HH, BB), 256, 0, stream>>>(ws_fused, ws_wb, out);
    pool_kernel<<<BB * CC, 256, 0, stream>>>(out, ws_pool);
    segate_kernel<<<1, 256, 0, stream>>>(ws_pool, se_w1, se_w2, ws_gate);
    elu_kernel<<<(BB * CC * HWW) / 256, 256, 0, stream>>>(out, ws_gate);
}

// Round 5
// 389.659 us; speedup vs baseline: 9.0634x; 1.1834x over previous
//
#include <hip/hip_runtime.h>
#include <math.h>

#define BB 4
#define CC 128
#define CRR 32
#define DD 24
#define HH 96
#define WW 320
#define HWW (HH*WW)   // 30720

typedef __attribute__((ext_vector_type(8))) short bs8;     // 8 bf16 (4 VGPR)
typedef __attribute__((ext_vector_type(4))) float f32x4;   // MFMA acc
typedef __attribute__((ext_vector_type(4))) int   i32x4;

static __device__ __forceinline__ unsigned short f2bf(float x) {
    unsigned int u = __float_as_uint(x);
    unsigned int r = (u + 0x7fffu + ((u >> 16) & 1u)) >> 16;   // RNE
    return (unsigned short)r;
}

// ---------------------------------------------------------------------------
// Repack q_w/k_w -> bf16 B-fragments.
// ---------------------------------------------------------------------------
__global__ __launch_bounds__(256) void repack_qk_kernel(
    const float* __restrict__ q_w, const float* __restrict__ k_w,
    unsigned short* __restrict__ wqk)
{
    int idx = blockIdx.x * 256 + threadIdx.x;    // < 8192
    int j   = idx & 7;
    int l   = (idx >> 3) & 63;
    int kc  = (idx >> 9) & 3;
    int ofh = (idx >> 11) & 1;
    int g   = idx >> 12;
    const float* w = g ? k_w : q_w;
    int oc = ofh * 16 + (l & 15);
    int ic = kc * 32 + (l >> 4) * 8 + j;
    wqk[idx] = f2bf(w[oc * CC + ic]);
}

// ---------------------------------------------------------------------------
// Repack ce_w (32->128) and redu_w (3x3) -> bf16 B-fragments (into dead ws_k).
// ---------------------------------------------------------------------------
__global__ __launch_bounds__(256) void repack2_kernel(
    const float* __restrict__ ce_w, const float* __restrict__ redu_w,
    unsigned short* __restrict__ wce, unsigned short* __restrict__ wb)
{
    int idx = blockIdx.x * 256 + threadIdx.x;   // < 4096 + 147456
    if (idx < 4096) {
        int j   = idx & 7;
        int l   = (idx >> 3) & 63;
        int ofg = (idx >> 9) & 7;
        int oc = ofg * 16 + (l & 15);
        int ic = (l >> 4) * 8 + j;
        wce[idx] = f2bf(ce_w[oc * CRR + ic]);
        return;
    }
    int i2 = idx - 4096;                         // redu part
    int j    = i2 & 7;
    int l    = (i2 >> 3) & 63;
    int rest = i2 >> 9;
    int ocf  = rest & 7;
    int kc   = (rest >> 3) & 3;
    int tap  = rest >> 5;            // 0..8
    int oc = ocf * 16 + (l & 15);
    int ic = kc * 32 + (l >> 4) * 8 + j;
    wb[i2] = f2bf(redu_w[(size_t)(oc * CC + ic) * 9 + tap]);
}

// ---------------------------------------------------------------------------
// Kernel 1: q/k 1x1 conv + bias + l2norm via bf16 MFMA.
// Output layout: CHANNEL-LAST  ws_q/ws_k[(b*HWW+px)*32 + c].
// ---------------------------------------------------------------------------
__global__ __launch_bounds__(256) void qk_mfma_kernel(
    const float* __restrict__ t_feat, const float* __restrict__ s_feat,
    const unsigned short* __restrict__ wqk,
    const float* __restrict__ q_b, const float* __restrict__ k_b,
    float* __restrict__ ws_q, float* __restrict__ ws_k)
{
    __shared__ __align__(16) unsigned char lds[2 * 64 * 16 * 16];   // 32 KB
    int tid  = threadIdx.x;
    int lane = tid & 63;
    int wid  = __builtin_amdgcn_readfirstlane(tid >> 6);
    int g = wid >> 1, ofh = wid & 1;
    int p0 = blockIdx.x * 64;
    int b = p0 / HWW, rem0 = p0 % HWW;

    for (int ci = tid; ci < 2 * 64 * 16; ci += 256) {
        int px   = ci & 63;
        int slot = (ci >> 6) & 15;
        int m    = ci >> 10;
        const float* src = (m ? s_feat : t_feat)
                         + (size_t)b * CC * HWW + (size_t)(slot * 8) * HWW + rem0 + px;
        i32x4 u;
        #pragma unroll
        for (int j = 0; j < 4; ++j) {
            unsigned short lo = f2bf(src[(size_t)(2 * j) * HWW]);
            unsigned short hi = f2bf(src[(size_t)(2 * j + 1) * HWW]);
            u[j] = (int)((unsigned int)lo | ((unsigned int)hi << 16));
        }
        int addr = m * 16384 + px * 256 + ((slot ^ (px & 7)) << 4);
        *(i32x4*)(lds + addr) = u;
    }
    __syncthreads();

    int l15 = lane & 15, l4 = lane >> 4;
    f32x4 acc[4];
    #pragma unroll
    for (int pf = 0; pf < 4; ++pf) acc[pf] = (f32x4){0.f, 0.f, 0.f, 0.f};

    const bs8* wp = (const bs8*)wqk + (size_t)(g * 2 + ofh) * 4 * 64;
    #pragma unroll
    for (int kc = 0; kc < 4; ++kc) {
        bs8 bf = wp[kc * 64 + lane];
        #pragma unroll
        for (int pf = 0; pf < 4; ++pf) {
            int addr = g * 16384 + (pf * 16 + l15) * 256 + (((kc * 4 + l4) ^ (l15 & 7)) << 4);
            bs8 a = *(const bs8*)(lds + addr);
            acc[pf] = __builtin_amdgcn_mfma_f32_16x16x32_bf16(a, bf, acc[pf], 0, 0, 0);
        }
    }
    __syncthreads();    // A tiles dead; reuse LDS as f32 [2][64][33]

    float* fl = (float*)lds;
    float bias = (g ? k_b : q_b)[ofh * 16 + l15];
    #pragma unroll
    for (int pf = 0; pf < 4; ++pf)
        #pragma unroll
        for (int r = 0; r < 4; ++r) {
            int px = pf * 16 + l4 * 4 + r;
            fl[(g * 64 + px) * 33 + ofh * 16 + l15] = acc[pf][r] + bias;
        }
    __syncthreads();

    if (tid < 128) {
        int gg = tid >> 6, px = tid & 63;
        const float* row = fl + (gg * 64 + px) * 33;
        float n = 0.f;
        #pragma unroll
        for (int oc = 0; oc < CRR; ++oc) n = fmaf(row[oc], row[oc], n);
        float inv = 1.f / fmaxf(sqrtf(n), 1e-12f);
        float* dst = (gg ? ws_k : ws_q) + ((size_t)b * HWW + rem0 + px) * CRR;
        #pragma unroll
        for (int j = 0; j < 8; ++j) {
            float4 v;
            v.x = row[j * 4 + 0] * inv;
            v.y = row[j * 4 + 1] * inv;
            v.z = row[j * 4 + 2] * inv;
            v.w = row[j * 4 + 3] * inv;
            *(float4*)(dst + j * 4) = v;
        }
    }
}

// ---------------------------------------------------------------------------
// Kernel 2: sim + softmax -> prob (d_out)  AND  cost -> ws_cost (channel-last).
// 128 px / block; 2 threads per px (16 ch each), combine via shfl_xor(32).
// All k/q/cost accesses are float4 on channel-last layout.
// ---------------------------------------------------------------------------
__global__ __launch_bounds__(256) void simcost_kernel(
    const float* __restrict__ directs, const int* __restrict__ image_shape,
    const float* __restrict__ ws_q, const float* __restrict__ ws_k,
    float* __restrict__ prob_out, float* __restrict__ ws_cost)
{
    int tid  = threadIdx.x;
    int half = (tid >> 5) & 1;
    int pxl  = (tid & 31) + ((tid >> 6) << 5);       // 0..127
    int p = blockIdx.x * 128 + pxl;
    int b = p / HWW, rem = p % HWW;
    int h = rem / WW, w = rem % WW;

    float rel = 640.0f / (float)image_shape[3];
    float fscale = rel * directs[b] * (float)(WW - 1);

    float4 q4[4];
    {
        const float4* qb = (const float4*)(ws_q + (size_t)p * CRR + half * 16);
        #pragma unroll
        for (int j = 0; j < 4; ++j) q4[j] = qb[j];
    }
    const float* krow = ws_k + ((size_t)b * HWW + h * WW) * CRR + half * 16;

    float sim[DD];
    #pragma unroll 2
    for (int d = 0; d < DD; ++d) {
        float disp = 0.3f * (float)d / 23.0f;
        float fx = fminf(fmaxf((float)w + disp * fscale, 0.f), (float)(WW - 1));
        int ix0 = (int)floorf(fx);
        int ix1 = min(ix0 + 1, WW - 1);
        float w1 = fx - (float)ix0;
        const float4* k0p = (const float4*)(krow + (size_t)ix0 * CRR);
        const float4* k1p = (const float4*)(krow + (size_t)ix1 * CRR);
        float s = 0.f;
        #pragma unroll
        for (int j = 0; j < 4; ++j) {
            float4 a = k0p[j], c = k1p[j];
            s = fmaf(q4[j].x, fmaf(w1, c.x - a.x, a.x), s);
            s = fmaf(q4[j].y, fmaf(w1, c.y - a.y, a.y), s);
            s = fmaf(q4[j].z, fmaf(w1, c.z - a.z, a.z), s);
            s = fmaf(q4[j].w, fmaf(w1, c.w - a.w, a.w), s);
        }
        s += __shfl_xor(s, 32, 64);
        sim[d] = s;
    }
    float m = sim[0];
    #pragma unroll
    for (int d = 1; d < DD; ++d) m = fmaxf(m, sim[d]);
    float sum = 0.f;
    #pragma unroll
    for (int d = 0; d < DD; ++d) { sim[d] = expf(sim[d] - m); sum += sim[d]; }
    float inv = 1.f / sum;
    #pragma unroll
    for (int d = 0; d < DD; ++d) sim[d] *= inv;        // prob
    if (!half) {
        #pragma unroll
        for (int d = 0; d < DD; ++d)
            prob_out[((size_t)b * DD + d) * HWW + rem] = sim[d];
    }

    float4 c4[4];
    #pragma unroll
    for (int j = 0; j < 4; ++j) c4[j] = (float4){0.f, 0.f, 0.f, 0.f};
    #pragma unroll 2
    for (int d = 0; d < DD; ++d) {
        float pr = sim[d];
        float disp = 0.3f * (float)d / 23.0f;
        float fx = fminf(fmaxf((float)w + disp * fscale, 0.f), (float)(WW - 1));
        int ix0 = (int)floorf(fx);
        int ix1 = min(ix0 + 1, WW - 1);
        float w1 = fx - (float)ix0;
        const float4* k0p = (const float4*)(krow + (size_t)ix0 * CRR);
        const float4* k1p = (const float4*)(krow + (size_t)ix1 * CRR);
        #pragma unroll
        for (int j = 0; j < 4; ++j) {
            float4 a = k0p[j], c = k1p[j];
            c4[j].x = fmaf(pr, fmaf(w1, c.x - a.x, a.x), c4[j].x);
            c4[j].y = fmaf(pr, fmaf(w1, c.y - a.y, a.y), c4[j].y);
            c4[j].z = fmaf(pr, fmaf(w1, c.z - a.z, a.z), c4[j].z);
            c4[j].w = fmaf(pr, fmaf(w1, c.w - a.w, a.w), c4[j].w);
        }
    }
    float4* cb = (float4*)(ws_cost + (size_t)p * CRR + half * 16);
    #pragma unroll
    for (int j = 0; j < 4; ++j) cb[j] = c4[j];
}

// ---------------------------------------------------------------------------
// Kernel 2c: cost-expand via MFMA + alpha + fuse -> ws_fused (plane layout).
// Block = 64 px, 4 waves; wave w owns oc [32w, 32w+32).
// ---------------------------------------------------------------------------
__global__ __launch_bounds__(256) void fuse_mfma_kernel(
    const float* __restrict__ t_feat, const unsigned short* __restrict__ wce,
    const float* __restrict__ ce_b, const float* __restrict__ fa_w,
    const float* __restrict__ fa_b,
    const float* __restrict__ ws_cost, float* __restrict__ ws_fused)
{
    __shared__ __align__(16) unsigned char ldsA[64 * 64];   // 64px x 32c bf16
    __shared__ float lds_pa[64][4];
    __shared__ float lds_alpha[64];
    int tid  = threadIdx.x;
    int lane = tid & 63;
    int wid  = __builtin_amdgcn_readfirstlane(tid >> 6);
    int p0 = blockIdx.x * 64;
    int b = p0 / HWW, rem0 = p0 % HWW;

    {   // stage cost tile bf16 (1 slot of 8ch per thread)
        int px = tid & 63, slot = tid >> 6;
        const float* src = ws_cost + (size_t)(p0 + px) * CRR + slot * 8;
        i32x4 u;
        #pragma unroll
        for (int j = 0; j < 4; ++j) {
            unsigned short lo = f2bf(src[2 * j]);
            unsigned short hi = f2bf(src[2 * j + 1]);
            u[j] = (int)((unsigned int)lo | ((unsigned int)hi << 16));
        }
        int addr = px * 64 + ((slot ^ (px & 3)) << 4);
        *(i32x4*)(ldsA + addr) = u;
    }
    __syncthreads();

    int l15 = lane & 15, l4 = lane >> 4;
    f32x4 acc[4][2];
    #pragma unroll
    for (int pf = 0; pf < 4; ++pf)
        #pragma unroll
        for (int of = 0; of < 2; ++of)
            acc[pf][of] = (f32x4){0.f, 0.f, 0.f, 0.f};

    const bs8* wp = (const bs8*)wce;
    #pragma unroll
    for (int pf = 0; pf < 4; ++pf) {
        int row = pf * 16 + l15;
        bs8 a = *(const bs8*)(ldsA + row * 64 + ((l4 ^ (l15 & 3)) << 4));
        #pragma unroll
        for (int of = 0; of < 2; ++of) {
            bs8 bf = wp[(wid * 2 + of) * 64 + lane];
            acc[pf][of] = __builtin_amdgcn_mfma_f32_16x16x32_bf16(a, bf, acc[pf][of], 0, 0, 0);
        }
    }

    // epilogue: ce = acc + ce_b; partial alpha = sum fa1*t + fa2*ce
    const float* tb = t_feat + (size_t)b * CC * HWW + rem0;
    float tvals[4][2][4];
    float pa[4][4];
    #pragma unroll
    for (int pf = 0; pf < 4; ++pf)
        #pragma unroll
        for (int r = 0; r < 4; ++r) pa[pf][r] = 0.f;

    #pragma unroll
    for (int pf = 0; pf < 4; ++pf)
        #pragma unroll
        for (int of = 0; of < 2; ++of) {
            int oc = wid * 32 + of * 16 + l15;
            float f1 = fa_w[oc], f2 = fa_w[CC + oc], cb = ce_b[oc];
            #pragma unroll
            for (int r = 0; r < 4; ++r) {
                int px = pf * 16 + l4 * 4 + r;
                float ce = acc[pf][of][r] + cb;
                acc[pf][of][r] = ce;
                float t = tb[(size_t)oc * HWW + px];
                tvals[pf][of][r] = t;
                pa[pf][r] = fmaf(f1, t, fmaf(f2, ce, pa[pf][r]));
            }
        }
    #pragma unroll
    for (int pf = 0; pf < 4; ++pf)
        #pragma unroll
        for (int r = 0; r < 4; ++r) {
            float v = pa[pf][r];
            #pragma unroll
            for (int msk = 1; msk < 16; msk <<= 1) v += __shfl_xor(v, msk, 64);
            if (l15 == 0) lds_pa[pf * 16 + l4 * 4 + r][wid] = v;
        }
    __syncthreads();
    if (tid < 64) {
        float s = lds_pa[tid][0] + lds_pa[tid][1] + lds_pa[tid][2] + lds_pa[tid][3] + fa_b[0];
        lds_alpha[tid] = 1.f / (1.f + expf(-s));
    }
    __syncthreads();

    #pragma unroll
    for (int pf = 0; pf < 4; ++pf)
        #pragma unroll
        for (int of = 0; of < 2; ++of) {
            int oc = wid * 32 + of * 16 + l15;
            #pragma unroll
            for (int r = 0; r < 4; ++r) {
                int px = pf * 16 + l4 * 4 + r;
                float alpha = lds_alpha[px];
                ws_fused[((size_t)b * CC + oc) * HWW + rem0 + px] =
                    alpha * tvals[pf][of][r] + (1.f - alpha) * acc[pf][of][r];
            }
        }
}

// ---------------------------------------------------------------------------
// Kernel 3: 3x3 reflect-pad conv (128->128) via bf16 MFMA implicit GEMM.
// ---------------------------------------------------------------------------
__global__ __launch_bounds__(256) void conv_mfma_kernel(
    const float* __restrict__ ws_fused, const unsigned short* __restrict__ wb,
    float* __restrict__ out_conv)
{
    __shared__ __align__(16) unsigned char lds[3 * 66 * 256];
    int tid  = threadIdx.x;
    int lane = tid & 63;
    int wid  = __builtin_amdgcn_readfirstlane(tid >> 6);
    int w0 = blockIdx.x * 64;
    int h  = blockIdx.y;
    int b  = blockIdx.z;

    const float* fb = ws_fused + (size_t)b * CC * HWW;

    for (int ci = tid; ci < 3 * 66 * 16; ci += 256) {
        int col  = ci % 66;
        int rs   = ci / 66;
        int slot = rs & 15;
        int row  = rs >> 4;
        int grow = h - 1 + row; grow = grow < 0 ? 1 : (grow > HH - 1 ? HH - 2 : grow);
        int gcol = w0 - 1 + col; gcol = gcol < 0 ? -gcol : (gcol > WW - 1 ? 2 * (WW - 1) - gcol : gcol);
        const float* src = fb + (size_t)(slot * 8) * HWW + grow * WW + gcol;
        i32x4 u;
        #pragma unroll
        for (int j = 0; j < 4; ++j) {
            unsigned short lo = f2bf(src[(size_t)(2 * j) * HWW]);
            unsigned short hi = f2bf(src[(size_t)(2 * j + 1) * HWW]);
            u[j] = (int)((unsigned int)lo | ((unsigned int)hi << 16));
        }
        int addr = (row * 66 + col) * 256 + ((slot ^ (col & 7)) << 4);
        *(i32x4*)(lds + addr) = u;
    }
    __syncthreads();

    f32x4 acc[4][2];
    #pragma unroll
    for (int pf = 0; pf < 4; ++pf)
        #pragma unroll
        for (int of = 0; of < 2; ++of)
            acc[pf][of] = (f32x4){0.f, 0.f, 0.f, 0.f};

    int l15 = lane & 15, l4 = lane >> 4;
    const bs8* wbp = (const bs8*)wb;

    #pragma unroll 1
    for (int tap = 0; tap < 9; ++tap) {
        int ky = tap / 3, kx = tap % 3;
        #pragma unroll
        for (int kc = 0; kc < 4; ++kc) {
            bs8 a[4];
            #pragma unroll
            for (int pf = 0; pf < 4; ++pf) {
                int colt = pf * 16 + l15 + kx;                  // 0..65
                int addr = (ky * 66 + colt) * 256 + (((kc * 4 + l4) ^ (colt & 7)) << 4);
                a[pf] = *(const bs8*)(lds + addr);
            }
            bs8 bf[2];
            #pragma unroll
            for (int of = 0; of < 2; ++of)
                bf[of] = wbp[((tap * 4 + kc) * 8 + wid * 2 + of) * 64 + lane];
            #pragma unroll
            for (int pf = 0; pf < 4; ++pf)
                #pragma unroll
                for (int of = 0; of < 2; ++of)
                    acc[pf][of] = __builtin_amdgcn_mfma_f32_16x16x32_bf16(
                        a[pf], bf[of], acc[pf][of], 0, 0, 0);
        }
    }

    #pragma unroll
    for (int pf = 0; pf < 4; ++pf)
        #pragma unroll
        for (int of = 0; of < 2; ++of) {
            int oc = wid * 32 + of * 16 + l15;
            #pragma unroll
            for (int r = 0; r < 4; ++r) {
                int px = pf * 16 + l4 * 4 + r;
                out_conv[((size_t)b * CC + oc) * HWW + h * WW + w0 + px] = acc[pf][of][r];
            }
        }
}

// ---------------------------------------------------------------------------
// Kernel 4: per-(b,c) plane mean
// ---------------------------------------------------------------------------
__global__ __launch_bounds__(256) void pool_kernel(
    const float* __restrict__ conv, float* __restrict__ pool)
{
    int plane = blockIdx.x;                // 0..511
    const float* p = conv + (size_t)plane * HWW;
    float s = 0.f;
    for (int i = threadIdx.x; i < HWW; i += 256) s += p[i];
    #pragma unroll
    for (int off = 32; off; off >>= 1) s += __shfl_down(s, off);
    __shared__ float wsum[4];
    if ((threadIdx.x & 63) == 0) wsum[threadIdx.x >> 6] = s;
    __syncthreads();
    if (threadIdx.x == 0)
        pool[plane] = (wsum[0] + wsum[1] + wsum[2] + wsum[3]) / (float)HWW;
}

// ---------------------------------------------------------------------------
// Kernel 5: SE MLP -> gate
// ---------------------------------------------------------------------------
__global__ __launch_bounds__(256) void segate_kernel(
    const float* __restrict__ pool, const float* __restrict__ w1,
    const float* __restrict__ w2, float* __restrict__ gate)
{
    __shared__ float hidden[BB * 8];
    int t = threadIdx.x;
    if (t < BB * 8) {
        int b = t / 8, r = t % 8;
        float s = 0.f;
        for (int c = 0; c < CC; ++c) s = fmaf(pool[b * CC + c], w1[r * CC + c], s);
        hidden[t] = fmaxf(s, 0.f);
    }
    __syncthreads();
    for (int idx = t; idx < BB * CC; idx += 256) {
        int b = idx / CC, c = idx % CC;
        float s = 0.f;
        #pragma unroll
        for (int r = 0; r < 8; ++r) s = fmaf(hidden[b * 8 + r], w2[c * 8 + r], s);
        gate[idx] = 1.f / (1.f + expf(-s));
    }
}

// ---------------------------------------------------------------------------
// Kernel 6: out = elu(conv * gate)  (in place on d_out)
// ---------------------------------------------------------------------------
__global__ __launch_bounds__(256) void elu_kernel(
    float* __restrict__ out, const float* __restrict__ gate)
{
    size_t i = (size_t)blockIdx.x * 256 + threadIdx.x;
    int plane = (int)(i / HWW);            // b*128+c
    float x = out[i] * gate[plane];
    out[i] = x > 0.f ? x : expm1f(x);
}

// ---------------------------------------------------------------------------
extern "C" void kernel_launch(void* const* d_in, const int* in_sizes, int n_in,
                              void* d_out, int out_size, void* d_ws, size_t ws_size,
                              hipStream_t stream)
{
    (void)in_sizes; (void)n_in; (void)out_size; (void)ws_size;
    const float* t_feat      = (const float*)d_in[0];
    const float* s_feat      = (const float*)d_in[1];
    const float* directs     = (const float*)d_in[2];
    const int*   image_shape = (const int*)d_in[3];
    const float* q_w  = (const float*)d_in[4];
    const float* q_b  = (const float*)d_in[5];
    const float* k_w  = (const float*)d_in[6];
    const float* k_b  = (const float*)d_in[7];
    const float* ce_w = (const float*)d_in[8];
    const float* ce_b = (const float*)d_in[9];
    const float* fa_w = (const float*)d_in[10];
    const float* fa_b = (const float*)d_in[11];
    const float* redu_w = (const float*)d_in[12];
    const float* se_w1  = (const float*)d_in[13];
    const float* se_w2  = (const float*)d_in[14];

    float* out      = (float*)d_out;
    float* prob_out = out + (size_t)BB * CC * HWW;   // second output region

    float* ws       = (float*)d_ws;
    float* ws_q     = ws;                                  // channel-last; dead after fuse
    float* ws_k     = ws + (size_t)BB * CRR * HWW;         // channel-last; dead after simcost
    float* ws_cost  = ws_q;                                // aliases ws_q (channel-last)
    float* ws_fused = ws + 2ull * BB * CRR * HWW;
    float* ws_pool  = ws_fused + (size_t)BB * CC * HWW;
    float* ws_gate  = ws_pool + BB * CC;
    unsigned short* ws_wqk = (unsigned short*)ws_fused;    // qk frags: alias pre-fuse ws_fused
    unsigned short* ws_wce = (unsigned short*)ws_k;        // ce frags: alias dead ws_k
    unsigned short* ws_wb  = ws_wce + 4096;                // redu frags: after wce

    repack_qk_kernel<<<32, 256, 0, stream>>>(q_w, k_w, ws_wqk);
    qk_mfma_kernel<<<BB * HWW / 64, 256, 0, stream>>>(t_feat, s_feat, ws_wqk,
                                                      q_b, k_b, ws_q, ws_k);
    simcost_kernel<<<BB * HWW / 128, 256, 0, stream>>>(directs, image_shape, ws_q, ws_k,
                                                       prob_out, ws_cost);
    repack2_kernel<<<592, 256, 0, stream>>>(ce_w, redu_w, ws_wce, ws_wb);
    fuse_mfma_kernel<<<BB * HWW / 64, 256, 0, stream>>>(t_feat, ws_wce, ce_b, fa_w, fa_b,
                                                        ws_cost, ws_fused);
    conv_mfma_kernel<<<dim3(WW / 64, HH, BB), 256, 0, stream>>>(ws_fused, ws_wb, out);
    pool_kernel<<<BB * CC, 256, 0, stream>>>(out, ws_pool);
    segate_kernel<<<1, 256, 0, stream>>>(ws_pool, se_w1, se_w2, ws_gate);
    elu_kernel<<<(BB * CC * HWW) / 256, 256, 0, stream>>>(out, ws_gate);
}

// Round 6
// 257.192 us; speedup vs baseline: 13.7315x; 1.5151x over previous
//
#include <hip/hip_runtime.h>
#include <math.h>

#define BB 4
#define CC 128
#define CRR 32
#define DD 24
#define HH 96
#define WW 320
#define HWW (HH*WW)   // 30720

typedef __attribute__((ext_vector_type(8))) short bs8;     // 8 bf16 (4 VGPR)
typedef __attribute__((ext_vector_type(4))) float f32x4;   // MFMA acc
typedef __attribute__((ext_vector_type(4))) int   i32x4;

static __device__ __forceinline__ unsigned short f2bf(float x) {
    unsigned int u = __float_as_uint(x);
    unsigned int r = (u + 0x7fffu + ((u >> 16) & 1u)) >> 16;   // RNE
    return (unsigned short)r;
}

// ---------------------------------------------------------------------------
// Repack q_w/k_w -> bf16 B-fragments.
// ---------------------------------------------------------------------------
__global__ __launch_bounds__(256) void repack_qk_kernel(
    const float* __restrict__ q_w, const float* __restrict__ k_w,
    unsigned short* __restrict__ wqk)
{
    int idx = blockIdx.x * 256 + threadIdx.x;    // < 8192
    int j   = idx & 7;
    int l   = (idx >> 3) & 63;
    int kc  = (idx >> 9) & 3;
    int ofh = (idx >> 11) & 1;
    int g   = idx >> 12;
    const float* w = g ? k_w : q_w;
    int oc = ofh * 16 + (l & 15);
    int ic = kc * 32 + (l >> 4) * 8 + j;
    wqk[idx] = f2bf(w[oc * CC + ic]);
}

// ---------------------------------------------------------------------------
// Repack ce_w (32->128) and redu_w (3x3) -> bf16 B-fragments (into dead ws_k).
// ---------------------------------------------------------------------------
__global__ __launch_bounds__(256) void repack2_kernel(
    const float* __restrict__ ce_w, const float* __restrict__ redu_w,
    unsigned short* __restrict__ wce, unsigned short* __restrict__ wb)
{
    int idx = blockIdx.x * 256 + threadIdx.x;   // < 4096 + 147456
    if (idx < 4096) {
        int j   = idx & 7;
        int l   = (idx >> 3) & 63;
        int ofg = (idx >> 9) & 7;
        int oc = ofg * 16 + (l & 15);
        int ic = (l >> 4) * 8 + j;
        wce[idx] = f2bf(ce_w[oc * CRR + ic]);
        return;
    }
    int i2 = idx - 4096;                         // redu part
    int j    = i2 & 7;
    int l    = (i2 >> 3) & 63;
    int rest = i2 >> 9;
    int ocf  = rest & 7;
    int kc   = (rest >> 3) & 3;
    int tap  = rest >> 5;            // 0..8
    int oc = ocf * 16 + (l & 15);
    int ic = kc * 32 + (l >> 4) * 8 + j;
    wb[i2] = f2bf(redu_w[(size_t)(oc * CC + ic) * 9 + tap]);
}

// ---------------------------------------------------------------------------
// Kernel 1: q/k 1x1 conv + bias + l2norm via bf16 MFMA.
// Output layout: CHANNEL-LAST  ws_q/ws_k[(b*HWW+px)*32 + c].
// ---------------------------------------------------------------------------
__global__ __launch_bounds__(256) void qk_mfma_kernel(
    const float* __restrict__ t_feat, const float* __restrict__ s_feat,
    const unsigned short* __restrict__ wqk,
    const float* __restrict__ q_b, const float* __restrict__ k_b,
    float* __restrict__ ws_q, float* __restrict__ ws_k)
{
    __shared__ __align__(16) unsigned char lds[2 * 64 * 16 * 16];   // 32 KB
    int tid  = threadIdx.x;
    int lane = tid & 63;
    int wid  = __builtin_amdgcn_readfirstlane(tid >> 6);
    int g = wid >> 1, ofh = wid & 1;
    int p0 = blockIdx.x * 64;
    int b = p0 / HWW, rem0 = p0 % HWW;

    for (int ci = tid; ci < 2 * 64 * 16; ci += 256) {
        int px   = ci & 63;
        int slot = (ci >> 6) & 15;
        int m    = ci >> 10;
        const float* src = (m ? s_feat : t_feat)
                         + (size_t)b * CC * HWW + (size_t)(slot * 8) * HWW + rem0 + px;
        i32x4 u;
        #pragma unroll
        for (int j = 0; j < 4; ++j) {
            unsigned short lo = f2bf(src[(size_t)(2 * j) * HWW]);
            unsigned short hi = f2bf(src[(size_t)(2 * j + 1) * HWW]);
            u[j] = (int)((unsigned int)lo | ((unsigned int)hi << 16));
        }
        int addr = m * 16384 + px * 256 + ((slot ^ (px & 7)) << 4);
        *(i32x4*)(lds + addr) = u;
    }
    __syncthreads();

    int l15 = lane & 15, l4 = lane >> 4;
    f32x4 acc[4];
    #pragma unroll
    for (int pf = 0; pf < 4; ++pf) acc[pf] = (f32x4){0.f, 0.f, 0.f, 0.f};

    const bs8* wp = (const bs8*)wqk + (size_t)(g * 2 + ofh) * 4 * 64;
    #pragma unroll
    for (int kc = 0; kc < 4; ++kc) {
        bs8 bf = wp[kc * 64 + lane];
        #pragma unroll
        for (int pf = 0; pf < 4; ++pf) {
            int addr = g * 16384 + (pf * 16 + l15) * 256 + (((kc * 4 + l4) ^ (l15 & 7)) << 4);
            bs8 a = *(const bs8*)(lds + addr);
            acc[pf] = __builtin_amdgcn_mfma_f32_16x16x32_bf16(a, bf, acc[pf], 0, 0, 0);
        }
    }
    __syncthreads();    // A tiles dead; reuse LDS as f32 [2][64][33]

    float* fl = (float*)lds;
    float bias = (g ? k_b : q_b)[ofh * 16 + l15];
    #pragma unroll
    for (int pf = 0; pf < 4; ++pf)
        #pragma unroll
        for (int r = 0; r < 4; ++r) {
            int px = pf * 16 + l4 * 4 + r;
            fl[(g * 64 + px) * 33 + ofh * 16 + l15] = acc[pf][r] + bias;
        }
    __syncthreads();

    if (tid < 128) {
        int gg = tid >> 6, px = tid & 63;
        const float* row = fl + (gg * 64 + px) * 33;
        float n = 0.f;
        #pragma unroll
        for (int oc = 0; oc < CRR; ++oc) n = fmaf(row[oc], row[oc], n);
        float inv = 1.f / fmaxf(sqrtf(n), 1e-12f);
        float* dst = (gg ? ws_k : ws_q) + ((size_t)b * HWW + rem0 + px) * CRR;
        #pragma unroll
        for (int j = 0; j < 8; ++j) {
            float4 v;
            v.x = row[j * 4 + 0] * inv;
            v.y = row[j * 4 + 1] * inv;
            v.z = row[j * 4 + 2] * inv;
            v.w = row[j * 4 + 3] * inv;
            *(float4*)(dst + j * 4) = v;
        }
    }
}

// ---------------------------------------------------------------------------
// Kernel 2: sim + (no-max) online softmax + cost, single gather pass over
// an LDS-staged k-row segment.
// Block = 256 thr = 64 px x 4 quarters (8 ch each). Grid = (5, 96, B).
// k slab: 166 cols x 32 ch f32, 16B slots XOR-swizzled by (col&7).
// |sim|<=1 (q,k unit vectors) so exp() needs no max subtraction.
// ---------------------------------------------------------------------------
#define SC_TILE 64
#define SC_HALO 50
#define SC_NCOLS (SC_TILE + 2*SC_HALO + 2)   // 166
__global__ __launch_bounds__(256) void simcost_kernel(
    const float* __restrict__ directs, const int* __restrict__ image_shape,
    const float* __restrict__ ws_q, const float* __restrict__ ws_k,
    float* __restrict__ prob_out, float* __restrict__ ws_cost)
{
    __shared__ __align__(16) unsigned char kl[SC_NCOLS * 128];
    int tid = threadIdx.x;
    int b = blockIdx.z, h = blockIdx.y, w0 = blockIdx.x * SC_TILE;
    int base = w0 - SC_HALO;

    const float* krow = ws_k + ((size_t)b * HWW + h * WW) * CRR;
    for (int i = tid; i < SC_NCOLS * 8; i += 256) {
        int col = i >> 3, j = i & 7;
        int gc = min(max(base + col, 0), WW - 1);
        float4 v = *(const float4*)(krow + (size_t)gc * CRR + j * 4);
        *(float4*)(kl + col * 128 + ((j ^ (col & 7)) << 4)) = v;
    }
    __syncthreads();

    int quarter = tid & 3;
    int pxl = tid >> 2;                       // 0..63
    int w = w0 + pxl;
    int rem = h * WW + w;
    size_t p = (size_t)b * HWW + rem;

    float rel = 640.0f / (float)image_shape[3];
    float fscale = rel * directs[b] * (float)(WW - 1);

    float4 q0, q1;
    {
        const float4* qb = (const float4*)(ws_q + p * CRR + quarter * 8);
        q0 = qb[0]; q1 = qb[1];
    }

    float e[DD];
    float Z = 0.f;
    float4 c0 = {0.f,0.f,0.f,0.f}, c1 = {0.f,0.f,0.f,0.f};
    int j0 = quarter * 2, j1 = quarter * 2 + 1;

    #pragma unroll
    for (int d = 0; d < DD; ++d) {
        float disp = 0.3f * (float)d / 23.0f;
        float fx = fminf(fmaxf((float)w + disp * fscale, 0.f), (float)(WW - 1));
        int ix0 = (int)floorf(fx);
        int ix1 = min(ix0 + 1, WW - 1);
        float w1 = fx - (float)ix0;
        int ca = ix0 - base, cb2 = ix1 - base;
        float4 a0 = *(const float4*)(kl + ca  * 128 + ((j0 ^ (ca  & 7)) << 4));
        float4 a1 = *(const float4*)(kl + ca  * 128 + ((j1 ^ (ca  & 7)) << 4));
        float4 b0 = *(const float4*)(kl + cb2 * 128 + ((j0 ^ (cb2 & 7)) << 4));
        float4 b1 = *(const float4*)(kl + cb2 * 128 + ((j1 ^ (cb2 & 7)) << 4));
        float4 w0v, w1v;
        w0v.x = fmaf(w1, b0.x - a0.x, a0.x);
        w0v.y = fmaf(w1, b0.y - a0.y, a0.y);
        w0v.z = fmaf(w1, b0.z - a0.z, a0.z);
        w0v.w = fmaf(w1, b0.w - a0.w, a0.w);
        w1v.x = fmaf(w1, b1.x - a1.x, a1.x);
        w1v.y = fmaf(w1, b1.y - a1.y, a1.y);
        w1v.z = fmaf(w1, b1.z - a1.z, a1.z);
        w1v.w = fmaf(w1, b1.w - a1.w, a1.w);
        float s = 0.f;
        s = fmaf(q0.x, w0v.x, s); s = fmaf(q0.y, w0v.y, s);
        s = fmaf(q0.z, w0v.z, s); s = fmaf(q0.w, w0v.w, s);
        s = fmaf(q1.x, w1v.x, s); s = fmaf(q1.y, w1v.y, s);
        s = fmaf(q1.z, w1v.z, s); s = fmaf(q1.w, w1v.w, s);
        s += __shfl_xor(s, 1, 64);
        s += __shfl_xor(s, 2, 64);
        float ee = __expf(s);
        e[d] = ee;
        Z += ee;
        c0.x = fmaf(ee, w0v.x, c0.x); c0.y = fmaf(ee, w0v.y, c0.y);
        c0.z = fmaf(ee, w0v.z, c0.z); c0.w = fmaf(ee, w0v.w, c0.w);
        c1.x = fmaf(ee, w1v.x, c1.x); c1.y = fmaf(ee, w1v.y, c1.y);
        c1.z = fmaf(ee, w1v.z, c1.z); c1.w = fmaf(ee, w1v.w, c1.w);
    }
    float inv = 1.f / Z;
    if (quarter == 0) {
        #pragma unroll
        for (int d = 0; d < DD; ++d)
            prob_out[((size_t)b * DD + d) * HWW + rem] = e[d] * inv;
    }
    c0.x *= inv; c0.y *= inv; c0.z *= inv; c0.w *= inv;
    c1.x *= inv; c1.y *= inv; c1.z *= inv; c1.w *= inv;
    float4* cb = (float4*)(ws_cost + p * CRR + quarter * 8);
    cb[0] = c0; cb[1] = c1;
}

// ---------------------------------------------------------------------------
// Kernel 2c: cost-expand via MFMA + alpha + fuse -> ws_fused (plane layout).
// Block = 64 px, 4 waves; wave w owns oc [32w, 32w+32).
// ---------------------------------------------------------------------------
__global__ __launch_bounds__(256) void fuse_mfma_kernel(
    const float* __restrict__ t_feat, const unsigned short* __restrict__ wce,
    const float* __restrict__ ce_b, const float* __restrict__ fa_w,
    const float* __restrict__ fa_b,
    const float* __restrict__ ws_cost, float* __restrict__ ws_fused)
{
    __shared__ __align__(16) unsigned char ldsA[64 * 64];   // 64px x 32c bf16
    __shared__ float lds_pa[64][4];
    __shared__ float lds_alpha[64];
    int tid  = threadIdx.x;
    int lane = tid & 63;
    int wid  = __builtin_amdgcn_readfirstlane(tid >> 6);
    int p0 = blockIdx.x * 64;
    int b = p0 / HWW, rem0 = p0 % HWW;

    {   // stage cost tile bf16 (1 slot of 8ch per thread)
        int px = tid & 63, slot = tid >> 6;
        const float* src = ws_cost + (size_t)(p0 + px) * CRR + slot * 8;
        i32x4 u;
        #pragma unroll
        for (int j = 0; j < 4; ++j) {
            unsigned short lo = f2bf(src[2 * j]);
            unsigned short hi = f2bf(src[2 * j + 1]);
            u[j] = (int)((unsigned int)lo | ((unsigned int)hi << 16));
        }
        int addr = px * 64 + ((slot ^ (px & 3)) << 4);
        *(i32x4*)(ldsA + addr) = u;
    }
    __syncthreads();

    int l15 = lane & 15, l4 = lane >> 4;
    f32x4 acc[4][2];
    #pragma unroll
    for (int pf = 0; pf < 4; ++pf)
        #pragma unroll
        for (int of = 0; of < 2; ++of)
            acc[pf][of] = (f32x4){0.f, 0.f, 0.f, 0.f};

    const bs8* wp = (const bs8*)wce;
    #pragma unroll
    for (int pf = 0; pf < 4; ++pf) {
        int row = pf * 16 + l15;
        bs8 a = *(const bs8*)(ldsA + row * 64 + ((l4 ^ (l15 & 3)) << 4));
        #pragma unroll
        for (int of = 0; of < 2; ++of) {
            bs8 bf = wp[(wid * 2 + of) * 64 + lane];
            acc[pf][of] = __builtin_amdgcn_mfma_f32_16x16x32_bf16(a, bf, acc[pf][of], 0, 0, 0);
        }
    }

    // epilogue: ce = acc + ce_b; partial alpha = sum fa1*t + fa2*ce
    const float* tb = t_feat + (size_t)b * CC * HWW + rem0;
    float tvals[4][2][4];
    float pa[4][4];
    #pragma unroll
    for (int pf = 0; pf < 4; ++pf)
        #pragma unroll
        for (int r = 0; r < 4; ++r) pa[pf][r] = 0.f;

    #pragma unroll
    for (int pf = 0; pf < 4; ++pf)
        #pragma unroll
        for (int of = 0; of < 2; ++of) {
            int oc = wid * 32 + of * 16 + l15;
            float f1 = fa_w[oc], f2 = fa_w[CC + oc], cb = ce_b[oc];
            #pragma unroll
            for (int r = 0; r < 4; ++r) {
                int px = pf * 16 + l4 * 4 + r;
                float ce = acc[pf][of][r] + cb;
                acc[pf][of][r] = ce;
                float t = tb[(size_t)oc * HWW + px];
                tvals[pf][of][r] = t;
                pa[pf][r] = fmaf(f1, t, fmaf(f2, ce, pa[pf][r]));
            }
        }
    #pragma unroll
    for (int pf = 0; pf < 4; ++pf)
        #pragma unroll
        for (int r = 0; r < 4; ++r) {
            float v = pa[pf][r];
            #pragma unroll
            for (int msk = 1; msk < 16; msk <<= 1) v += __shfl_xor(v, msk, 64);
            if (l15 == 0) lds_pa[pf * 16 + l4 * 4 + r][wid] = v;
        }
    __syncthreads();
    if (tid < 64) {
        float s = lds_pa[tid][0] + lds_pa[tid][1] + lds_pa[tid][2] + lds_pa[tid][3] + fa_b[0];
        lds_alpha[tid] = 1.f / (1.f + expf(-s));
    }
    __syncthreads();

    #pragma unroll
    for (int pf = 0; pf < 4; ++pf)
        #pragma unroll
        for (int of = 0; of < 2; ++of) {
            int oc = wid * 32 + of * 16 + l15;
            #pragma unroll
            for (int r = 0; r < 4; ++r) {
                int px = pf * 16 + l4 * 4 + r;
                float alpha = lds_alpha[px];
                ws_fused[((size_t)b * CC + oc) * HWW + rem0 + px] =
                    alpha * tvals[pf][of][r] + (1.f - alpha) * acc[pf][of][r];
            }
        }
}

// ---------------------------------------------------------------------------
// Kernel 3: 3x3 reflect-pad conv (128->128) via bf16 MFMA implicit GEMM.
// ---------------------------------------------------------------------------
__global__ __launch_bounds__(256) void conv_mfma_kernel(
    const float* __restrict__ ws_fused, const unsigned short* __restrict__ wb,
    float* __restrict__ out_conv)
{
    __shared__ __align__(16) unsigned char lds[3 * 66 * 256];
    int tid  = threadIdx.x;
    int lane = tid & 63;
    int wid  = __builtin_amdgcn_readfirstlane(tid >> 6);
    int w0 = blockIdx.x * 64;
    int h  = blockIdx.y;
    int b  = blockIdx.z;

    const float* fb = ws_fused + (size_t)b * CC * HWW;

    for (int ci = tid; ci < 3 * 66 * 16; ci += 256) {
        int col  = ci % 66;
        int rs   = ci / 66;
        int slot = rs & 15;
        int row  = rs >> 4;
        int grow = h - 1 + row; grow = grow < 0 ? 1 : (grow > HH - 1 ? HH - 2 : grow);
        int gcol = w0 - 1 + col; gcol = gcol < 0 ? -gcol : (gcol > WW - 1 ? 2 * (WW - 1) - gcol : gcol);
        const float* src = fb + (size_t)(slot * 8) * HWW + grow * WW + gcol;
        i32x4 u;
        #pragma unroll
        for (int j = 0; j < 4; ++j) {
            unsigned short lo = f2bf(src[(size_t)(2 * j) * HWW]);
            unsigned short hi = f2bf(src[(size_t)(2 * j + 1) * HWW]);
            u[j] = (int)((unsigned int)lo | ((unsigned int)hi << 16));
        }
        int addr = (row * 66 + col) * 256 + ((slot ^ (col & 7)) << 4);
        *(i32x4*)(lds + addr) = u;
    }
    __syncthreads();

    f32x4 acc[4][2];
    #pragma unroll
    for (int pf = 0; pf < 4; ++pf)
        #pragma unroll
        for (int of = 0; of < 2; ++of)
            acc[pf][of] = (f32x4){0.f, 0.f, 0.f, 0.f};

    int l15 = lane & 15, l4 = lane >> 4;
    const bs8* wbp = (const bs8*)wb;

    #pragma unroll 1
    for (int tap = 0; tap < 9; ++tap) {
        int ky = tap / 3, kx = tap % 3;
        #pragma unroll
        for (int kc = 0; kc < 4; ++kc) {
            bs8 a[4];
            #pragma unroll
            for (int pf = 0; pf < 4; ++pf) {
                int colt = pf * 16 + l15 + kx;                  // 0..65
                int addr = (ky * 66 + colt) * 256 + (((kc * 4 + l4) ^ (colt & 7)) << 4);
                a[pf] = *(const bs8*)(lds + addr);
            }
            bs8 bf[2];
            #pragma unroll
            for (int of = 0; of < 2; ++of)
                bf[of] = wbp[((tap * 4 + kc) * 8 + wid * 2 + of) * 64 + lane];
            #pragma unroll
            for (int pf = 0; pf < 4; ++pf)
                #pragma unroll
                for (int of = 0; of < 2; ++of)
                    acc[pf][of] = __builtin_amdgcn_mfma_f32_16x16x32_bf16(
                        a[pf], bf[of], acc[pf][of], 0, 0, 0);
        }
    }

    #pragma unroll
    for (int pf = 0; pf < 4; ++pf)
        #pragma unroll
        for (int of = 0; of < 2; ++of) {
            int oc = wid * 32 + of * 16 + l15;
            #pragma unroll
            for (int r = 0; r < 4; ++r) {
                int px = pf * 16 + l4 * 4 + r;
                out_conv[((size_t)b * CC + oc) * HWW + h * WW + w0 + px] = acc[pf][of][r];
            }
        }
}

// ---------------------------------------------------------------------------
// Kernel 4: per-(b,c) plane mean
// ---------------------------------------------------------------------------
__global__ __launch_bounds__(256) void pool_kernel(
    const float* __restrict__ conv, float* __restrict__ pool)
{
    int plane = blockIdx.x;                // 0..511
    const float* p = conv + (size_t)plane * HWW;
    float s = 0.f;
    for (int i = threadIdx.x; i < HWW; i += 256) s += p[i];
    #pragma unroll
    for (int off = 32; off; off >>= 1) s += __shfl_down(s, off);
    __shared__ float wsum[4];
    if ((threadIdx.x & 63) == 0) wsum[threadIdx.x >> 6] = s;
    __syncthreads();
    if (threadIdx.x == 0)
        pool[plane] = (wsum[0] + wsum[1] + wsum[2] + wsum[3]) / (float)HWW;
}

// ---------------------------------------------------------------------------
// Kernel 5: SE MLP -> gate
// ---------------------------------------------------------------------------
__global__ __launch_bounds__(256) void segate_kernel(
    const float* __restrict__ pool, const float* __restrict__ w1,
    const float* __restrict__ w2, float* __restrict__ gate)
{
    __shared__ float hidden[BB * 8];
    int t = threadIdx.x;
    if (t < BB * 8) {
        int b = t / 8, r = t % 8;
        float s = 0.f;
        for (int c = 0; c < CC; ++c) s = fmaf(pool[b * CC + c], w1[r * CC + c], s);
        hidden[t] = fmaxf(s, 0.f);
    }
    __syncthreads();
    for (int idx = t; idx < BB * CC; idx += 256) {
        int b = idx / CC, c = idx % CC;
        float s = 0.f;
        #pragma unroll
        for (int r = 0; r < 8; ++r) s = fmaf(hidden[b * 8 + r], w2[c * 8 + r], s);
        gate[idx] = 1.f / (1.f + expf(-s));
    }
}

// ---------------------------------------------------------------------------
// Kernel 6: out = elu(conv * gate)  (in place on d_out)
// ---------------------------------------------------------------------------
__global__ __launch_bounds__(256) void elu_kernel(
    float* __restrict__ out, const float* __restrict__ gate)
{
    size_t i = (size_t)blockIdx.x * 256 + threadIdx.x;
    int plane = (int)(i / HWW);            // b*128+c
    float x = out[i] * gate[plane];
    out[i] = x > 0.f ? x : expm1f(x);
}

// ---------------------------------------------------------------------------
extern "C" void kernel_launch(void* const* d_in, const int* in_sizes, int n_in,
                              void* d_out, int out_size, void* d_ws, size_t ws_size,
                              hipStream_t stream)
{
    (void)in_sizes; (void)n_in; (void)out_size; (void)ws_size;
    const float* t_feat      = (const float*)d_in[0];
    const float* s_feat      = (const float*)d_in[1];
    const float* directs     = (const float*)d_in[2];
    const int*   image_shape = (const int*)d_in[3];
    const float* q_w  = (const float*)d_in[4];
    const float* q_b  = (const float*)d_in[5];
    const float* k_w  = (const float*)d_in[6];
    const float* k_b  = (const float*)d_in[7];
    const float* ce_w = (const float*)d_in[8];
    const float* ce_b = (const float*)d_in[9];
    const float* fa_w = (const float*)d_in[10];
    const float* fa_b = (const float*)d_in[11];
    const float* redu_w = (const float*)d_in[12];
    const float* se_w1  = (const float*)d_in[13];
    const float* se_w2  = (const float*)d_in[14];

    float* out      = (float*)d_out;
    float* prob_out = out + (size_t)BB * CC * HWW;   // second output region

    float* ws       = (float*)d_ws;
    float* ws_q     = ws;                                  // channel-last; dead after fuse
    float* ws_k     = ws + (size_t)BB * CRR * HWW;         // channel-last; dead after simcost
    float* ws_cost  = ws_q;                                // aliases ws_q (channel-last)
    float* ws_fused = ws + 2ull * BB * CRR * HWW;
    float* ws_pool  = ws_fused + (size_t)BB * CC * HWW;
    float* ws_gate  = ws_pool + BB * CC;
    unsigned short* ws_wqk = (unsigned short*)ws_fused;    // qk frags: alias pre-fuse ws_fused
    unsigned short* ws_wce = (unsigned short*)ws_k;        // ce frags: alias dead ws_k
    unsigned short* ws_wb  = ws_wce + 4096;                // redu frags: after wce

    repack_qk_kernel<<<32, 256, 0, stream>>>(q_w, k_w, ws_wqk);
    qk_mfma_kernel<<<BB * HWW / 64, 256, 0, stream>>>(t_feat, s_feat, ws_wqk,
                                                      q_b, k_b, ws_q, ws_k);
    simcost_kernel<<<dim3(WW / SC_TILE, HH, BB), 256, 0, stream>>>(
        directs, image_shape, ws_q, ws_k, prob_out, ws_cost);
    repack2_kernel<<<592, 256, 0, stream>>>(ce_w, redu_w, ws_wce, ws_wb);
    fuse_mfma_kernel<<<BB * HWW / 64, 256, 0, stream>>>(t_feat, ws_wce, ce_b, fa_w, fa_b,
                                                        ws_cost, ws_fused);
    conv_mfma_kernel<<<dim3(WW / 64, HH, BB), 256, 0, stream>>>(ws_fused, ws_wb, out);
    pool_kernel<<<BB * CC, 256, 0, stream>>>(out, ws_pool);
    segate_kernel<<<1, 256, 0, stream>>>(ws_pool, se_w1, se_w2, ws_gate);
    elu_kernel<<<(BB * CC * HWW) / 256, 256, 0, stream>>>(out, ws_gate);
}

// Round 7
// 214.642 us; speedup vs baseline: 16.4536x; 1.1982x over previous
//
#include <hip/hip_runtime.h>
#include <math.h>

#define BB 4
#define CC 128
#define CRR 32
#define DD 24
#define HH 96
#define WW 320
#define HWW (HH*WW)   // 30720

typedef __attribute__((ext_vector_type(8))) short bs8;     // 8 bf16 (4 VGPR)
typedef __attribute__((ext_vector_type(4))) float f32x4;   // MFMA acc
typedef __attribute__((ext_vector_type(4))) int   i32x4;

static __device__ __forceinline__ unsigned short f2bf(float x) {
    unsigned int u = __float_as_uint(x);
    unsigned int r = (u + 0x7fffu + ((u >> 16) & 1u)) >> 16;   // RNE
    return (unsigned short)r;
}

// ---------------------------------------------------------------------------
// Repack q_w/k_w -> bf16 fragments (A-operand layout: row=l&15 -> oc).
// ---------------------------------------------------------------------------
__global__ __launch_bounds__(256) void repack_qk_kernel(
    const float* __restrict__ q_w, const float* __restrict__ k_w,
    unsigned short* __restrict__ wqk)
{
    int idx = blockIdx.x * 256 + threadIdx.x;    // < 8192
    int j   = idx & 7;
    int l   = (idx >> 3) & 63;
    int kc  = (idx >> 9) & 3;
    int ofh = (idx >> 11) & 1;
    int g   = idx >> 12;
    const float* w = g ? k_w : q_w;
    int oc = ofh * 16 + (l & 15);
    int ic = kc * 32 + (l >> 4) * 8 + j;
    wqk[idx] = f2bf(w[oc * CC + ic]);
}

// ---------------------------------------------------------------------------
// Repack ce_w (32->128) and redu_w (3x3) -> bf16 fragments (into dead ws_k).
// ---------------------------------------------------------------------------
__global__ __launch_bounds__(256) void repack2_kernel(
    const float* __restrict__ ce_w, const float* __restrict__ redu_w,
    unsigned short* __restrict__ wce, unsigned short* __restrict__ wb)
{
    int idx = blockIdx.x * 256 + threadIdx.x;   // < 4096 + 147456
    if (idx < 4096) {
        int j   = idx & 7;
        int l   = (idx >> 3) & 63;
        int ofg = (idx >> 9) & 7;
        int oc = ofg * 16 + (l & 15);
        int ic = (l >> 4) * 8 + j;
        wce[idx] = f2bf(ce_w[oc * CRR + ic]);
        return;
    }
    int i2 = idx - 4096;                         // redu part
    int j    = i2 & 7;
    int l    = (i2 >> 3) & 63;
    int rest = i2 >> 9;
    int ocf  = rest & 7;
    int kc   = (rest >> 3) & 3;
    int tap  = rest >> 5;            // 0..8
    int oc = ocf * 16 + (l & 15);
    int ic = kc * 32 + (l >> 4) * 8 + j;
    wb[i2] = f2bf(redu_w[(size_t)(oc * CC + ic) * 9 + tap]);
}

// ---------------------------------------------------------------------------
// Kernel 1: q/k 1x1 conv + bias + l2norm via bf16 MFMA (weights = A operand).
// D: row = oc_local (l4*4+r), col = px (pf*16+l15).
// Output layout: CHANNEL-LAST  ws_q/ws_k[(b*HWW+px)*32 + c].
// ---------------------------------------------------------------------------
__global__ __launch_bounds__(256) void qk_mfma_kernel(
    const float* __restrict__ t_feat, const float* __restrict__ s_feat,
    const unsigned short* __restrict__ wqk,
    const float* __restrict__ q_b, const float* __restrict__ k_b,
    float* __restrict__ ws_q, float* __restrict__ ws_k)
{
    __shared__ __align__(16) unsigned char lds[2 * 64 * 16 * 16];   // 32 KB
    int tid  = threadIdx.x;
    int lane = tid & 63;
    int wid  = __builtin_amdgcn_readfirstlane(tid >> 6);
    int g = wid >> 1, ofh = wid & 1;
    int p0 = blockIdx.x * 64;
    int b = p0 / HWW, rem0 = p0 % HWW;

    for (int ci = tid; ci < 2 * 64 * 16; ci += 256) {
        int px   = ci & 63;
        int slot = (ci >> 6) & 15;
        int m    = ci >> 10;
        const float* src = (m ? s_feat : t_feat)
                         + (size_t)b * CC * HWW + (size_t)(slot * 8) * HWW + rem0 + px;
        i32x4 u;
        #pragma unroll
        for (int j = 0; j < 4; ++j) {
            unsigned short lo = f2bf(src[(size_t)(2 * j) * HWW]);
            unsigned short hi = f2bf(src[(size_t)(2 * j + 1) * HWW]);
            u[j] = (int)((unsigned int)lo | ((unsigned int)hi << 16));
        }
        int addr = m * 16384 + px * 256 + ((slot ^ (px & 7)) << 4);
        *(i32x4*)(lds + addr) = u;
    }
    __syncthreads();

    int l15 = lane & 15, l4 = lane >> 4;
    f32x4 acc[4];
    #pragma unroll
    for (int pf = 0; pf < 4; ++pf) acc[pf] = (f32x4){0.f, 0.f, 0.f, 0.f};

    const bs8* wp = (const bs8*)wqk + (size_t)(g * 2 + ofh) * 4 * 64;
    #pragma unroll
    for (int kc = 0; kc < 4; ++kc) {
        bs8 bf = wp[kc * 64 + lane];
        #pragma unroll
        for (int pf = 0; pf < 4; ++pf) {
            int addr = g * 16384 + (pf * 16 + l15) * 256 + (((kc * 4 + l4) ^ (l15 & 7)) << 4);
            bs8 a = *(const bs8*)(lds + addr);
            acc[pf] = __builtin_amdgcn_mfma_f32_16x16x32_bf16(bf, a, acc[pf], 0, 0, 0);
        }
    }

    // bias + per-px partial norms (this wave covers 16 oc)
    float4 bias4 = *(const float4*)((g ? k_b : q_b) + ofh * 16 + l4 * 4);
    float np[4];
    #pragma unroll
    for (int pf = 0; pf < 4; ++pf) {
        float s = 0.f;
        #pragma unroll
        for (int r = 0; r < 4; ++r) {
            float v = acc[pf][r] + ((const float*)&bias4)[r];
            acc[pf][r] = v;
            s = fmaf(v, v, s);
        }
        s += __shfl_xor(s, 16, 64);
        s += __shfl_xor(s, 32, 64);
        np[pf] = s;
    }
    __syncthreads();    // A tiles dead; reuse LDS for norm exchange
    float* fl = (float*)lds;   // [4 waves][64 px]
    if (l4 == 0) {
        #pragma unroll
        for (int pf = 0; pf < 4; ++pf)
            fl[(g * 2 + ofh) * 64 + pf * 16 + l15] = np[pf];
    }
    __syncthreads();

    float* dst = (g ? ws_k : ws_q) + ((size_t)b * HWW + rem0) * CRR;
    #pragma unroll
    for (int pf = 0; pf < 4; ++pf) {
        int px = pf * 16 + l15;
        float tot = fl[(g * 2) * 64 + px] + fl[(g * 2 + 1) * 64 + px];
        float inv = 1.f / fmaxf(sqrtf(tot), 1e-12f);
        float4 v;
        v.x = acc[pf][0] * inv; v.y = acc[pf][1] * inv;
        v.z = acc[pf][2] * inv; v.w = acc[pf][3] * inv;
        *(float4*)(dst + (size_t)px * CRR + ofh * 16 + l4 * 4) = v;
    }
}

// ---------------------------------------------------------------------------
// Kernel 2: sim + (no-max) online softmax + cost, single gather pass over
// an LDS-staged k-row segment.  (unchanged from round 6)
// ---------------------------------------------------------------------------
#define SC_TILE 64
#define SC_HALO 50
#define SC_NCOLS (SC_TILE + 2*SC_HALO + 2)   // 166
__global__ __launch_bounds__(256) void simcost_kernel(
    const float* __restrict__ directs, const int* __restrict__ image_shape,
    const float* __restrict__ ws_q, const float* __restrict__ ws_k,
    float* __restrict__ prob_out, float* __restrict__ ws_cost)
{
    __shared__ __align__(16) unsigned char kl[SC_NCOLS * 128];
    int tid = threadIdx.x;
    int b = blockIdx.z, h = blockIdx.y, w0 = blockIdx.x * SC_TILE;
    int base = w0 - SC_HALO;

    const float* krow = ws_k + ((size_t)b * HWW + h * WW) * CRR;
    for (int i = tid; i < SC_NCOLS * 8; i += 256) {
        int col = i >> 3, j = i & 7;
        int gc = min(max(base + col, 0), WW - 1);
        float4 v = *(const float4*)(krow + (size_t)gc * CRR + j * 4);
        *(float4*)(kl + col * 128 + ((j ^ (col & 7)) << 4)) = v;
    }
    __syncthreads();

    int quarter = tid & 3;
    int pxl = tid >> 2;                       // 0..63
    int w = w0 + pxl;
    int rem = h * WW + w;
    size_t p = (size_t)b * HWW + rem;

    float rel = 640.0f / (float)image_shape[3];
    float fscale = rel * directs[b] * (float)(WW - 1);

    float4 q0, q1;
    {
        const float4* qb = (const float4*)(ws_q + p * CRR + quarter * 8);
        q0 = qb[0]; q1 = qb[1];
    }

    float e[DD];
    float Z = 0.f;
    float4 c0 = {0.f,0.f,0.f,0.f}, c1 = {0.f,0.f,0.f,0.f};
    int j0 = quarter * 2, j1 = quarter * 2 + 1;

    #pragma unroll
    for (int d = 0; d < DD; ++d) {
        float disp = 0.3f * (float)d / 23.0f;
        float fx = fminf(fmaxf((float)w + disp * fscale, 0.f), (float)(WW - 1));
        int ix0 = (int)floorf(fx);
        int ix1 = min(ix0 + 1, WW - 1);
        float w1 = fx - (float)ix0;
        int ca = ix0 - base, cb2 = ix1 - base;
        float4 a0 = *(const float4*)(kl + ca  * 128 + ((j0 ^ (ca  & 7)) << 4));
        float4 a1 = *(const float4*)(kl + ca  * 128 + ((j1 ^ (ca  & 7)) << 4));
        float4 b0 = *(const float4*)(kl + cb2 * 128 + ((j0 ^ (cb2 & 7)) << 4));
        float4 b1 = *(const float4*)(kl + cb2 * 128 + ((j1 ^ (cb2 & 7)) << 4));
        float4 w0v, w1v;
        w0v.x = fmaf(w1, b0.x - a0.x, a0.x);
        w0v.y = fmaf(w1, b0.y - a0.y, a0.y);
        w0v.z = fmaf(w1, b0.z - a0.z, a0.z);
        w0v.w = fmaf(w1, b0.w - a0.w, a0.w);
        w1v.x = fmaf(w1, b1.x - a1.x, a1.x);
        w1v.y = fmaf(w1, b1.y - a1.y, a1.y);
        w1v.z = fmaf(w1, b1.z - a1.z, a1.z);
        w1v.w = fmaf(w1, b1.w - a1.w, a1.w);
        float s = 0.f;
        s = fmaf(q0.x, w0v.x, s); s = fmaf(q0.y, w0v.y, s);
        s = fmaf(q0.z, w0v.z, s); s = fmaf(q0.w, w0v.w, s);
        s = fmaf(q1.x, w1v.x, s); s = fmaf(q1.y, w1v.y, s);
        s = fmaf(q1.z, w1v.z, s); s = fmaf(q1.w, w1v.w, s);
        s += __shfl_xor(s, 1, 64);
        s += __shfl_xor(s, 2, 64);
        float ee = __expf(s);
        e[d] = ee;
        Z += ee;
        c0.x = fmaf(ee, w0v.x, c0.x); c0.y = fmaf(ee, w0v.y, c0.y);
        c0.z = fmaf(ee, w0v.z, c0.z); c0.w = fmaf(ee, w0v.w, c0.w);
        c1.x = fmaf(ee, w1v.x, c1.x); c1.y = fmaf(ee, w1v.y, c1.y);
        c1.z = fmaf(ee, w1v.z, c1.z); c1.w = fmaf(ee, w1v.w, c1.w);
    }
    float inv = 1.f / Z;
    if (quarter == 0) {
        #pragma unroll
        for (int d = 0; d < DD; ++d)
            prob_out[((size_t)b * DD + d) * HWW + rem] = e[d] * inv;
    }
    c0.x *= inv; c0.y *= inv; c0.z *= inv; c0.w *= inv;
    c1.x *= inv; c1.y *= inv; c1.z *= inv; c1.w *= inv;
    float4* cb = (float4*)(ws_cost + p * CRR + quarter * 8);
    cb[0] = c0; cb[1] = c1;
}

// ---------------------------------------------------------------------------
// Kernel 2c: cost-expand via MFMA (weights = A) + alpha + fuse.
// D: row = oc_local, col = px.  Writes fused as bf16 CHANNEL-LAST [px][128].
// ---------------------------------------------------------------------------
__global__ __launch_bounds__(256) void fuse_mfma_kernel(
    const float* __restrict__ t_feat, const unsigned short* __restrict__ wce,
    const float* __restrict__ ce_b, const float* __restrict__ fa_w,
    const float* __restrict__ fa_b,
    const float* __restrict__ ws_cost, unsigned short* __restrict__ fused)
{
    __shared__ __align__(16) unsigned char ldsA[64 * 64];   // 64px x 32c bf16
    __shared__ float lds_pa[64][4];
    __shared__ float lds_alpha[64];
    int tid  = threadIdx.x;
    int lane = tid & 63;
    int wid  = __builtin_amdgcn_readfirstlane(tid >> 6);
    int p0 = blockIdx.x * 64;
    int b = p0 / HWW, rem0 = p0 % HWW;

    {   // stage cost tile bf16 (1 slot of 8ch per thread)
        int px = tid & 63, slot = tid >> 6;
        const float* src = ws_cost + (size_t)(p0 + px) * CRR + slot * 8;
        i32x4 u;
        #pragma unroll
        for (int j = 0; j < 4; ++j) {
            unsigned short lo = f2bf(src[2 * j]);
            unsigned short hi = f2bf(src[2 * j + 1]);
            u[j] = (int)((unsigned int)lo | ((unsigned int)hi << 16));
        }
        int addr = px * 64 + ((slot ^ (px & 3)) << 4);
        *(i32x4*)(ldsA + addr) = u;
    }
    __syncthreads();

    int l15 = lane & 15, l4 = lane >> 4;
    f32x4 acc[4][2];
    #pragma unroll
    for (int pf = 0; pf < 4; ++pf)
        #pragma unroll
        for (int of = 0; of < 2; ++of)
            acc[pf][of] = (f32x4){0.f, 0.f, 0.f, 0.f};

    const bs8* wp = (const bs8*)wce;
    #pragma unroll
    for (int pf = 0; pf < 4; ++pf) {
        int row = pf * 16 + l15;
        bs8 a = *(const bs8*)(ldsA + row * 64 + ((l4 ^ (l15 & 3)) << 4));
        #pragma unroll
        for (int of = 0; of < 2; ++of) {
            bs8 bf = wp[(wid * 2 + of) * 64 + lane];
            acc[pf][of] = __builtin_amdgcn_mfma_f32_16x16x32_bf16(bf, a, acc[pf][of], 0, 0, 0);
        }
    }

    // epilogue: oc = wid*32 + of*16 + l4*4 + r ; px = pf*16 + l15
    const float* tb = t_feat + (size_t)b * CC * HWW + rem0;
    float tv[4][2][4];
    float pa[4];
    #pragma unroll
    for (int pf = 0; pf < 4; ++pf) pa[pf] = 0.f;

    #pragma unroll
    for (int of = 0; of < 2; ++of) {
        int ocb = wid * 32 + of * 16 + l4 * 4;
        float4 cb4 = *(const float4*)(ce_b + ocb);
        float4 f14 = *(const float4*)(fa_w + ocb);
        float4 f24 = *(const float4*)(fa_w + CC + ocb);
        #pragma unroll
        for (int pf = 0; pf < 4; ++pf) {
            int px = pf * 16 + l15;
            #pragma unroll
            for (int r = 0; r < 4; ++r) {
                float ce = acc[pf][of][r] + ((const float*)&cb4)[r];
                acc[pf][of][r] = ce;
                float t = tb[(size_t)(ocb + r) * HWW + px];
                tv[pf][of][r] = t;
                pa[pf] = fmaf(((const float*)&f14)[r], t,
                              fmaf(((const float*)&f24)[r], ce, pa[pf]));
            }
        }
    }
    #pragma unroll
    for (int pf = 0; pf < 4; ++pf) {
        float v = pa[pf];
        v += __shfl_xor(v, 16, 64);
        v += __shfl_xor(v, 32, 64);
        if (l4 == 0) lds_pa[pf * 16 + l15][wid] = v;
    }
    __syncthreads();
    if (tid < 64) {
        float s = lds_pa[tid][0] + lds_pa[tid][1] + lds_pa[tid][2] + lds_pa[tid][3] + fa_b[0];
        lds_alpha[tid] = 1.f / (1.f + expf(-s));
    }
    __syncthreads();

    #pragma unroll
    for (int pf = 0; pf < 4; ++pf) {
        int px = pf * 16 + l15;
        float alpha = lds_alpha[px];
        unsigned short* dst = fused + (size_t)(p0 + px) * CC;
        #pragma unroll
        for (int of = 0; of < 2; ++of) {
            int ocb = wid * 32 + of * 16 + l4 * 4;
            float v0 = alpha * tv[pf][of][0] + (1.f - alpha) * acc[pf][of][0];
            float v1 = alpha * tv[pf][of][1] + (1.f - alpha) * acc[pf][of][1];
            float v2 = alpha * tv[pf][of][2] + (1.f - alpha) * acc[pf][of][2];
            float v3 = alpha * tv[pf][of][3] + (1.f - alpha) * acc[pf][of][3];
            uint2 u;
            u.x = (unsigned int)f2bf(v0) | ((unsigned int)f2bf(v1) << 16);
            u.y = (unsigned int)f2bf(v2) | ((unsigned int)f2bf(v3) << 16);
            *(uint2*)(dst + ocb) = u;
        }
    }
}

// ---------------------------------------------------------------------------
// Kernel 3: 3x3 reflect-pad conv via bf16 MFMA (weights = A operand).
// Input: fused bf16 channel-last [b*HWW+px][128] — staging is pure 16B copy.
// D: row = oc_local, col = px -> coalesced 64B output stores.
// ---------------------------------------------------------------------------
__global__ __launch_bounds__(256) void conv_mfma_kernel(
    const unsigned short* __restrict__ fused, const unsigned short* __restrict__ wb,
    float* __restrict__ out_conv)
{
    __shared__ __align__(16) unsigned char lds[3 * 66 * 256];
    int tid  = threadIdx.x;
    int lane = tid & 63;
    int wid  = __builtin_amdgcn_readfirstlane(tid >> 6);
    int w0 = blockIdx.x * 64;
    int h  = blockIdx.y;
    int b  = blockIdx.z;

    const unsigned short* fb = fused + (size_t)b * HWW * CC;

    // stage: slot-fastest -> 16 lanes cover one pixel's 256B (coalesced read,
    // conflict-free LDS write)
    for (int ci = tid; ci < 3 * 66 * 16; ci += 256) {
        int row  = ci / 1056;
        int r2   = ci - row * 1056;
        int col  = r2 >> 4;
        int slot = r2 & 15;
        int grow = h - 1 + row; grow = grow < 0 ? 1 : (grow > HH - 1 ? HH - 2 : grow);
        int gcol = w0 - 1 + col; gcol = gcol < 0 ? -gcol : (gcol > WW - 1 ? 2 * (WW - 1) - gcol : gcol);
        i32x4 u = *(const i32x4*)(fb + (size_t)(grow * WW + gcol) * CC + slot * 8);
        *(i32x4*)(lds + (row * 66 + col) * 256 + ((slot ^ (col & 7)) << 4)) = u;
    }
    __syncthreads();

    f32x4 acc[4][2];
    #pragma unroll
    for (int pf = 0; pf < 4; ++pf)
        #pragma unroll
        for (int of = 0; of < 2; ++of)
            acc[pf][of] = (f32x4){0.f, 0.f, 0.f, 0.f};

    int l15 = lane & 15, l4 = lane >> 4;
    const bs8* wbp = (const bs8*)wb;

    #pragma unroll 1
    for (int tap = 0; tap < 9; ++tap) {
        int ky = tap / 3, kx = tap % 3;
        #pragma unroll
        for (int kc = 0; kc < 4; ++kc) {
            bs8 a[4];
            #pragma unroll
            for (int pf = 0; pf < 4; ++pf) {
                int colt = pf * 16 + l15 + kx;                  // 0..65
                int addr = (ky * 66 + colt) * 256 + (((kc * 4 + l4) ^ (colt & 7)) << 4);
                a[pf] = *(const bs8*)(lds + addr);
            }
            bs8 bf[2];
            #pragma unroll
            for (int of = 0; of < 2; ++of)
                bf[of] = wbp[((tap * 4 + kc) * 8 + wid * 2 + of) * 64 + lane];
            #pragma unroll
            for (int pf = 0; pf < 4; ++pf)
                #pragma unroll
                for (int of = 0; of < 2; ++of)
                    acc[pf][of] = __builtin_amdgcn_mfma_f32_16x16x32_bf16(
                        bf[of], a[pf], acc[pf][of], 0, 0, 0);
        }
    }

    // D: row = oc_local = l4*4+r, col = px = pf*16+l15
    #pragma unroll
    for (int pf = 0; pf < 4; ++pf) {
        int px = pf * 16 + l15;
        #pragma unroll
        for (int of = 0; of < 2; ++of) {
            #pragma unroll
            for (int r = 0; r < 4; ++r) {
                int oc = wid * 32 + of * 16 + l4 * 4 + r;
                out_conv[((size_t)b * CC + oc) * HWW + h * WW + w0 + px] = acc[pf][of][r];
            }
        }
    }
}

// ---------------------------------------------------------------------------
// Kernel 4: per-(b,c) plane mean
// ---------------------------------------------------------------------------
__global__ __launch_bounds__(256) void pool_kernel(
    const float* __restrict__ conv, float* __restrict__ pool)
{
    int plane = blockIdx.x;                // 0..511
    const float* p = conv + (size_t)plane * HWW;
    float s = 0.f;
    for (int i = threadIdx.x; i < HWW; i += 256) s += p[i];
    #pragma unroll
    for (int off = 32; off; off >>= 1) s += __shfl_down(s, off);
    __shared__ float wsum[4];
    if ((threadIdx.x & 63) == 0) wsum[threadIdx.x >> 6] = s;
    __syncthreads();
    if (threadIdx.x == 0)
        pool[plane] = (wsum[0] + wsum[1] + wsum[2] + wsum[3]) / (float)HWW;
}

// ---------------------------------------------------------------------------
// Kernel 5: SE MLP -> gate
// ---------------------------------------------------------------------------
__global__ __launch_bounds__(256) void segate_kernel(
    const float* __restrict__ pool, const float* __restrict__ w1,
    const float* __restrict__ w2, float* __restrict__ gate)
{
    __shared__ float hidden[BB * 8];
    int t = threadIdx.x;
    if (t < BB * 8) {
        int b = t / 8, r = t % 8;
        float s = 0.f;
        for (int c = 0; c < CC; ++c) s = fmaf(pool[b * CC + c], w1[r * CC + c], s);
        hidden[t] = fmaxf(s, 0.f);
    }
    __syncthreads();
    for (int idx = t; idx < BB * CC; idx += 256) {
        int b = idx / CC, c = idx % CC;
        float s = 0.f;
        #pragma unroll
        for (int r = 0; r < 8; ++r) s = fmaf(hidden[b * 8 + r], w2[c * 8 + r], s);
        gate[idx] = 1.f / (1.f + expf(-s));
    }
}

// ---------------------------------------------------------------------------
// Kernel 6: out = elu(conv * gate)  (in place on d_out)
// ---------------------------------------------------------------------------
__global__ __launch_bounds__(256) void elu_kernel(
    float* __restrict__ out, const float* __restrict__ gate)
{
    size_t i = (size_t)blockIdx.x * 256 + threadIdx.x;
    int plane = (int)(i / HWW);            // b*128+c
    float x = out[i] * gate[plane];
    out[i] = x > 0.f ? x : expm1f(x);
}

// ---------------------------------------------------------------------------
extern "C" void kernel_launch(void* const* d_in, const int* in_sizes, int n_in,
                              void* d_out, int out_size, void* d_ws, size_t ws_size,
                              hipStream_t stream)
{
    (void)in_sizes; (void)n_in; (void)out_size; (void)ws_size;
    const float* t_feat      = (const float*)d_in[0];
    const float* s_feat      = (const float*)d_in[1];
    const float* directs     = (const float*)d_in[2];
    const int*   image_shape = (const int*)d_in[3];
    const float* q_w  = (const float*)d_in[4];
    const float* q_b  = (const float*)d_in[5];
    const float* k_w  = (const float*)d_in[6];
    const float* k_b  = (const float*)d_in[7];
    const float* ce_w = (const float*)d_in[8];
    const float* ce_b = (const float*)d_in[9];
    const float* fa_w = (const float*)d_in[10];
    const float* fa_b = (const float*)d_in[11];
    const float* redu_w = (const float*)d_in[12];
    const float* se_w1  = (const float*)d_in[13];
    const float* se_w2  = (const float*)d_in[14];

    float* out      = (float*)d_out;
    float* prob_out = out + (size_t)BB * CC * HWW;   // second output region

    float* ws       = (float*)d_ws;
    float* ws_q     = ws;                                  // channel-last; dead after fuse
    float* ws_k     = ws + (size_t)BB * CRR * HWW;         // channel-last; dead after simcost
    float* ws_cost  = ws_q;                                // aliases ws_q (channel-last)
    unsigned short* ws_fused = (unsigned short*)(ws + 2ull * BB * CRR * HWW);  // bf16 ch-last
    float* ws_pool  = ws + 2ull * BB * CRR * HWW + (size_t)BB * CC * HWW;
    float* ws_gate  = ws_pool + BB * CC;
    unsigned short* ws_wqk = (unsigned short*)ws_fused;    // qk frags: alias pre-fuse fused
    unsigned short* ws_wce = (unsigned short*)ws_k;        // ce frags: alias dead ws_k
    unsigned short* ws_wb  = ws_wce + 4096;                // redu frags: after wce

    repack_qk_kernel<<<32, 256, 0, stream>>>(q_w, k_w, ws_wqk);
    qk_mfma_kernel<<<BB * HWW / 64, 256, 0, stream>>>(t_feat, s_feat, ws_wqk,
                                                      q_b, k_b, ws_q, ws_k);
    simcost_kernel<<<dim3(WW / SC_TILE, HH, BB), 256, 0, stream>>>(
        directs, image_shape, ws_q, ws_k, prob_out, ws_cost);
    repack2_kernel<<<592, 256, 0, stream>>>(ce_w, redu_w, ws_wce, ws_wb);
    fuse_mfma_kernel<<<BB * HWW / 64, 256, 0, stream>>>(t_feat, ws_wce, ce_b, fa_w, fa_b,
                                                        ws_cost, ws_fused);
    conv_mfma_kernel<<<dim3(WW / 64, HH, BB), 256, 0, stream>>>(ws_fused, ws_wb, out);
    pool_kernel<<<BB * CC, 256, 0, stream>>>(out, ws_pool);
    segate_kernel<<<1, 256, 0, stream>>>(ws_pool, se_w1, se_w2, ws_gate);
    elu_kernel<<<(BB * CC * HWW) / 256, 256, 0, stream>>>(out, ws_gate);
}